// Round 11
// baseline (582.002 us; speedup 1.0000x reference)
//
#include <hip/hip_runtime.h>

typedef __attribute__((ext_vector_type(8))) short bfrag;   // 8 bf16 (4 VGPRs)
typedef __attribute__((ext_vector_type(4))) float ffrag;   // 4 fp32

__device__ __forceinline__ unsigned short f2b(float f){
  unsigned int u = __float_as_uint(f);
  return (unsigned short)((u + 0x7FFFu + ((u >> 16) & 1u)) >> 16);
}
// shifted softplus via v_exp/v_log (both base-2 on gfx950)
__device__ __forceinline__ float actf(float v){
  float e = __builtin_amdgcn_exp2f(-fabsf(v)*1.44269504088896341f);
  return fmaxf(v, 0.f) + __builtin_amdgcn_logf(1.f + e)*0.69314718055994531f - 0.69314718055994531f;
}

// ---------- small utility kernels ----------
__global__ __launch_bounds__(256) void k_zero(float* p, int n){
  int i = blockIdx.x*256 + threadIdx.x;
  if (i < n) p[i] = 0.f;
}

__global__ __launch_bounds__(256) void k_dij_count(
    const float* __restrict__ R, const int* __restrict__ idx_i, const int* __restrict__ idx_j,
    float* __restrict__ DijF, float* __restrict__ Dout, int* __restrict__ counts, int P){
  int p = blockIdx.x*256 + threadIdx.x;
  if (p >= P) return;
  int i = idx_i[p], j = idx_j[p];
  float dx = R[i*3+0] - R[j*3+0];
  float dy = R[i*3+1] - R[j*3+1];
  float dz = R[i*3+2] - R[j*3+2];
  float D = sqrtf(fmaxf(dx*dx + dy*dy + dz*dz, 0.f));
  DijF[p] = D;
  Dout[p] = D;
  atomicAdd(&counts[i], 1);
}

// hierarchical scan
__global__ __launch_bounds__(256) void k_scanA(const int* __restrict__ counts,
    int* __restrict__ locEx, int* __restrict__ bsum, int N){
  __shared__ int buf[256];
  int tid = threadIdx.x, idx = blockIdx.x*256 + tid;
  int v = (idx < N) ? counts[idx] : 0;
  buf[tid] = v;
  __syncthreads();
  for (int off = 1; off < 256; off <<= 1){
    int t = (tid >= off) ? buf[tid-off] : 0;
    __syncthreads();
    buf[tid] += t;
    __syncthreads();
  }
  if (idx < N) locEx[idx] = buf[tid] - v;
  if (tid == 255) bsum[blockIdx.x] = buf[255];
}
__global__ __launch_bounds__(64) void k_scanB(int* __restrict__ bsum,
    int* __restrict__ boff, int nb){
  if (threadIdx.x == 0){
    int acc = 0;
    for (int i = 0; i < nb; ++i){ boff[i] = acc; acc += bsum[i]; }
    boff[nb] = acc;
  }
}
__global__ __launch_bounds__(256) void k_scanC(const int* __restrict__ locEx,
    const int* __restrict__ boff, int* __restrict__ starts, int* __restrict__ cursor,
    int N, int nb){
  int idx = blockIdx.x*256 + threadIdx.x;
  if (idx < N){
    int s = locEx[idx] + boff[blockIdx.x];
    starts[idx] = s; cursor[idx] = s;
  }
  if (idx == 0) starts[N] = boff[nb];
}

__global__ __launch_bounds__(256) void k_scatter(const int* __restrict__ idx_i,
    const int* __restrict__ idx_j, const float* __restrict__ DijF,
    int* __restrict__ cursor, int* __restrict__ i_s, int* __restrict__ j_s,
    float* __restrict__ D_s, int P){
  int p = blockIdx.x*256 + threadIdx.x;
  if (p >= P) return;
  int i = idx_i[p];
  int pos = atomicAdd(&cursor[i], 1);
  i_s[pos] = i;
  j_s[pos] = idx_j[p];
  D_s[pos] = DijF[p];
}

__global__ __launch_bounds__(256) void k_rbf(
    const float* __restrict__ D_s, const float* __restrict__ cent, const float* __restrict__ wid,
    unsigned short* __restrict__ rbf_s, int P){
  int gid = blockIdx.x*256 + threadIdx.x;
  if (gid >= P*64) return;
  int t = gid >> 6, k = gid & 63;
  float D = D_s[t];
  float xc = D * 0.1f;
  float cut = 0.f;
  if (xc < 1.f){
    float x3 = xc*xc*xc, x4 = x3*xc, x5 = x4*xc;
    cut = 1.f - 6.f*x5 + 15.f*x4 - 10.f*x3;
  }
  float tt = expf(-D) - cent[k];
  rbf_s[gid] = f2b(cut * expf(-wid[k]*tt*tt));
}

// k2f B-frag prep -- unchanged, HW-verified
__global__ __launch_bounds__(256) void k_prep(const float* __restrict__ k2f,
    unsigned short* __restrict__ k2fP){
  int gid = blockIdx.x*256 + threadIdx.x;
  if (gid >= 5120) return;
  int l = gid & 63, fr = (gid >> 6) & 15, b = gid >> 10;
  int tile = fr >> 1, kh = fr & 1;
  const float* src = k2f + (size_t)b*64*128;
  int n = tile*16 + (l & 15);
  int kbase = kh*32 + (l >> 4)*8;
  ushort4 o0, o1;
  o0.x = f2b(src[(kbase+0)*128+n]); o0.y = f2b(src[(kbase+1)*128+n]);
  o0.z = f2b(src[(kbase+2)*128+n]); o0.w = f2b(src[(kbase+3)*128+n]);
  o1.x = f2b(src[(kbase+4)*128+n]); o1.y = f2b(src[(kbase+5)*128+n]);
  o1.z = f2b(src[(kbase+6)*128+n]); o1.w = f2b(src[(kbase+7)*128+n]);
  ushort4* dst = (ushort4*)(k2fP + (size_t)gid*8);
  dst[0] = o0; dst[1] = o1;
}

// ALL 75 weight matrices repacked in ONE launch (mapping as round 9)
__global__ __launch_bounds__(256) void k_prepAll(
    const float* __restrict__ riW1, const float* __restrict__ riW2,
    const float* __restrict__ dW,   const float* __restrict__ raW1,
    const float* __restrict__ raW2, const float* __restrict__ roW1,
    const float* __restrict__ roW2, const float* __restrict__ Wi,
    const float* __restrict__ Wj,   unsigned short* __restrict__ WBall){
  int gid = blockIdx.x*256 + threadIdx.x;
  if (gid >= 75*2048) return;
  int i = gid >> 11, r = gid & 2047;
  const float* S;
  int slot;
  if (i < 15)      { S = riW1 + (size_t)i*16384;      slot = (i/3)*15 + 2*(i%3); }
  else if (i < 30) { int j=i-15; S = riW2 + (size_t)j*16384; slot = (j/3)*15 + 2*(j%3) + 1; }
  else if (i < 35) { int j=i-30; S = dW   + (size_t)j*16384; slot = j*15 + 6; }
  else if (i < 45) { int j=i-35; S = raW1 + (size_t)j*16384; slot = (j/2)*15 + 7 + 2*(j%2); }
  else if (i < 55) { int j=i-45; S = raW2 + (size_t)j*16384; slot = (j/2)*15 + 8 + 2*(j%2); }
  else if (i < 60) { int j=i-55; S = roW1 + (size_t)j*16384; slot = j*15 + 11; }
  else if (i < 65) { int j=i-60; S = roW2 + (size_t)j*16384; slot = j*15 + 12; }
  else if (i < 70) { int j=i-65; S = Wi   + (size_t)j*16384; slot = ((j==0)?4:(j-1))*15 + 13; }
  else             { int j=i-70; S = Wj   + (size_t)j*16384; slot = ((j==0)?4:(j-1))*15 + 14; }
  int fr = r >> 6, l = r & 63;
  int T = fr >> 2, k0 = fr & 3;
  int n = T*16 + (l & 15);
  int kbase = k0*32 + (l >> 4)*8;
  unsigned short* D = WBall + ((size_t)slot*2048 + r)*8;
  ushort4 o0, o1;
  o0.x=f2b(S[(kbase+0)*128+n]); o0.y=f2b(S[(kbase+1)*128+n]);
  o0.z=f2b(S[(kbase+2)*128+n]); o0.w=f2b(S[(kbase+3)*128+n]);
  o1.x=f2b(S[(kbase+4)*128+n]); o1.y=f2b(S[(kbase+5)*128+n]);
  o1.z=f2b(S[(kbase+6)*128+n]); o1.w=f2b(S[(kbase+7)*128+n]);
  ((ushort4*)D)[0]=o0; ((ushort4*)D)[1]=o1;
}

// outW[b] [128x2] -> padded B-frags -- unchanged
__global__ __launch_bounds__(256) void k_prepO(const float* __restrict__ outW,
    unsigned short* __restrict__ outWB){
  int gid = blockIdx.x*256 + threadIdx.x;
  if (gid >= 5*256) return;
  int b = gid >> 8, r = gid & 255;
  int l = r & 63;
  int col = l & 15;
  int k0 = r >> 6;
  int kbase = k0*32 + (l >> 4)*8;
  ushort4 o0 = {0,0,0,0}, o1 = {0,0,0,0};
  if (col < 2){
    const float* S = outW + (size_t)b*256;
    o0.x=f2b(S[(kbase+0)*2+col]); o0.y=f2b(S[(kbase+1)*2+col]);
    o0.z=f2b(S[(kbase+2)*2+col]); o0.w=f2b(S[(kbase+3)*2+col]);
    o1.x=f2b(S[(kbase+4)*2+col]); o1.y=f2b(S[(kbase+5)*2+col]);
    o1.z=f2b(S[(kbase+6)*2+col]); o1.w=f2b(S[(kbase+7)*2+col]);
  }
  unsigned short* D = outWB + ((size_t)b*256 + r)*8;
  ((ushort4*)D)[0]=o0; ((ushort4*)D)[1]=o1;
}

// ---------- MFMA tile machinery ----------
// phase1 (2 waves, 4 col-tiles each)
__device__ __forceinline__ void mmtile(const unsigned short* tile,
    const unsigned short* __restrict__ WB, int w, int l, ffrag C[4]){
  int m = l & 15, q = l >> 4;
  bfrag A[4];
  #pragma unroll
  for (int k0 = 0; k0 < 4; ++k0)
    A[k0] = *(const bfrag*)(tile + m*136 + k0*32 + q*8);
  #pragma unroll
  for (int tt = 0; tt < 4; ++tt){
    ffrag c = {0.f,0.f,0.f,0.f};
    const bfrag* bp = (const bfrag*)(WB + (((w*4+tt)*4)*64 + l)*8);
    #pragma unroll
    for (int k0 = 0; k0 < 4; ++k0)
      c = __builtin_amdgcn_mfma_f32_16x16x32_bf16(A[k0], bp[k0*64], c, 0, 0, 0);
    C[tt] = c;
  }
}

// phase2 helpers: B in registers (8 bfrags per stage), wave w covers col-tiles w*2,w*2+1
__device__ __forceinline__ void loadB8(const unsigned short* __restrict__ WB,
    int w, int l, bfrag* B){
  #pragma unroll
  for (int tt = 0; tt < 2; ++tt)
    #pragma unroll
    for (int k0 = 0; k0 < 4; ++k0)
      B[tt*4+k0] = *(const bfrag*)(WB + ((size_t)((((w*2+tt)*4)+k0)*64 + l))*8);
}
__device__ __forceinline__ void mmB(const unsigned short* tile, const bfrag* B,
    int l, ffrag C[2]){
  int m = l & 15, q = l >> 4;
  bfrag A[4];
  #pragma unroll
  for (int k0 = 0; k0 < 4; ++k0)
    A[k0] = *(const bfrag*)(tile + m*136 + k0*32 + q*8);
  #pragma unroll
  for (int tt = 0; tt < 2; ++tt){
    ffrag c = {0.f,0.f,0.f,0.f};
    #pragma unroll
    for (int k0 = 0; k0 < 4; ++k0)
      c = __builtin_amdgcn_mfma_f32_16x16x32_bf16(A[k0], B[tt*4+k0], c, 0, 0, 0);
    C[tt] = c;
  }
}

// phase1: x = emb[Z]; m_g = act(act(x)@Wi0+bi0); xjb = act(act(x)@Wj0+bj0)
__global__ __launch_bounds__(128) void k_phase1m(
    const int* __restrict__ Z, const float* __restrict__ emb,
    const unsigned short* __restrict__ WB45,
    const float* __restrict__ bi0, const float* __restrict__ bj0,
    float* __restrict__ x_g, float* __restrict__ m_g, float* __restrict__ xjb_g, int N){
  __shared__ unsigned short tile[16*136];
  int tid = threadIdx.x, w = tid >> 6, l = tid & 63;
  int m = l & 15, q = l >> 4, rbase = blockIdx.x*16;
  #pragma unroll
  for (int r = 0; r < 4; ++r){
    int row = rbase + q*4 + r;
    int z = Z[row];
    #pragma unroll
    for (int tt = 0; tt < 4; ++tt){
      int c = (w*4+tt)*16 + m;
      float v = emb[(size_t)z*128 + c];
      x_g[(size_t)row*128 + c] = v;
      tile[(q*4+r)*136 + c] = f2b(actf(v));
    }
  }
  __syncthreads();
  ffrag C[4];
  mmtile(tile, WB45 + 13*16384, w, l, C);
  #pragma unroll
  for (int tt = 0; tt < 4; ++tt){
    int c = (w*4+tt)*16 + m;
    float bb = bi0[c];
    #pragma unroll
    for (int r = 0; r < 4; ++r)
      m_g[(size_t)(rbase + q*4 + r)*128 + c] = actf(C[tt][r] + bb);
  }
  mmtile(tile, WB45 + 14*16384, w, l, C);
  #pragma unroll
  for (int tt = 0; tt < 4; ++tt){
    int c = (w*4+tt)*16 + m;
    float bb = bj0[c];
    #pragma unroll
    for (int r = 0; r < 4; ++r)
      xjb_g[(size_t)(rbase + q*4 + r)*128 + c] = actf(C[tt][r] + bb);
  }
}

// MFMA pair-message -- unchanged from round 10 (bench-validated)
__global__ __launch_bounds__(256) void k_pairmsg2(
    const unsigned short* __restrict__ rbf_s, const unsigned short* __restrict__ k2fP,
    const int* __restrict__ i_s, const int* __restrict__ j_s,
    const float* __restrict__ xj, float* __restrict__ m_g, int P){
  __shared__ float G[4][16*130];
  int tid = threadIdx.x, w = tid >> 6, l = tid & 63;
  float* Gw = &G[w][0];
  bfrag B[16];
  #pragma unroll
  for (int t = 0; t < 8; ++t){
    #pragma unroll
    for (int kh = 0; kh < 2; ++kh)
      B[t*2+kh] = *(const bfrag*)(k2fP + (size_t)((t*2+kh)*64 + l)*8);
  }
  int wstart = (blockIdx.x*4 + w)*128;
  if (wstart >= P) return;
  int row16 = l & 15, quad = l >> 4;
  float a0 = 0.f, a1 = 0.f;
  int iCur = -1;
  bfrag A0 = *(const bfrag*)(rbf_s + (size_t)(wstart + row16)*64 + quad*8);
  bfrag A1 = *(const bfrag*)(rbf_s + (size_t)(wstart + row16)*64 + 32 + quad*8);
  int4 iv[4], jv[4];
  #pragma unroll
  for (int g = 0; g < 4; ++g){
    iv[g] = *(const int4*)(i_s + wstart + g*4);
    jv[g] = *(const int4*)(j_s + wstart + g*4);
  }
  #pragma unroll 1
  for (int bi2 = 0; bi2 < 8; ++bi2){
    int bt = wstart + bi2*16;
    const int* ip = (const int*)iv;
    const int* jp = (const int*)jv;
    float2 xv[16];
    #pragma unroll
    for (int k = 0; k < 16; ++k)
      xv[k] = *(const float2*)(xj + (size_t)jp[k]*128 + 2*l);
    #pragma unroll
    for (int t = 0; t < 8; ++t){
      ffrag C = {0.f,0.f,0.f,0.f};
      C = __builtin_amdgcn_mfma_f32_16x16x32_bf16(A0, B[t*2],   C, 0, 0, 0);
      C = __builtin_amdgcn_mfma_f32_16x16x32_bf16(A1, B[t*2+1], C, 0, 0, 0);
      #pragma unroll
      for (int r = 0; r < 4; ++r)
        Gw[(quad*4+r)*130 + t*16 + row16] = C[r];
    }
    bfrag nA0, nA1;
    int4 niv[4], njv[4];
    if (bi2 < 7){
      int btn = bt + 16;
      nA0 = *(const bfrag*)(rbf_s + (size_t)(btn + row16)*64 + quad*8);
      nA1 = *(const bfrag*)(rbf_s + (size_t)(btn + row16)*64 + 32 + quad*8);
      #pragma unroll
      for (int g = 0; g < 4; ++g){
        niv[g] = *(const int4*)(i_s + btn + g*4);
        njv[g] = *(const int4*)(j_s + btn + g*4);
      }
    }
    #pragma unroll
    for (int k = 0; k < 16; ++k){
      int i = ip[k];
      if (i != iCur){
        if (iCur >= 0){
          unsafeAtomicAdd(&m_g[(size_t)iCur*128 + 2*l],     a0);
          unsafeAtomicAdd(&m_g[(size_t)iCur*128 + 2*l + 1], a1);
        }
        iCur = i; a0 = 0.f; a1 = 0.f;
      }
      float g0 = Gw[k*130 + 2*l], g1 = Gw[k*130 + 2*l + 1];
      a0 = fmaf(g0, xv[k].x, a0);
      a1 = fmaf(g1, xv[k].y, a1);
    }
    if (bi2 < 7){
      A0 = nA0; A1 = nA1;
      #pragma unroll
      for (int g = 0; g < 4; ++g){ iv[g] = niv[g]; jv[g] = njv[g]; }
    }
  }
  if (iCur >= 0){
    unsafeAtomicAdd(&m_g[(size_t)iCur*128 + 2*l],     a0);
    unsafeAtomicAdd(&m_g[(size_t)iCur*128 + 2*l + 1], a1);
  }
}

// ---------- phase 2: TWO 16-row tiles per block (32 rows), 4 waves ----------
// Per stage: one barrier, two independent MFMA chains + epilogues (2x ILP).
// W slots: riW1[l]=2l riW2[l]=2l+1 dW=6 raW1=7+2l raW2=8+2l roW1=11 roW2=12 WiN=13 WjN=14
// Stage seq (HASNEXT): 0..10,13,14,11,12 ; (!HASNEXT): 0..10,11,12
template<int HASNEXT, int NH>
__global__ __launch_bounds__(256) void k_phase2m(
    float* __restrict__ m_g, float* __restrict__ x_g, float* __restrict__ xjb_g,
    const unsigned short* __restrict__ WBb,
    const float* __restrict__ rib1, const float* __restrict__ rib2,
    const float* __restrict__ db, const float* __restrict__ u,
    const float* __restrict__ rab1, const float* __restrict__ rab2,
    const float* __restrict__ rob1, const float* __restrict__ rob2,
    const float* __restrict__ biN, const float* __restrict__ bjN,
    const unsigned short* __restrict__ outWBb,
    float* __restrict__ Ea, float* __restrict__ Qa,
    float* __restrict__ last2, float* __restrict__ nh, int N){
  __shared__ unsigned short tiles[2][32*136];
  __shared__ float biasS[16*128];
  int tid = threadIdx.x, w = tid >> 6, l = tid & 63;
  int m = l & 15, q = l >> 4, rbase = blockIdx.x*32;
  ffrag mC[2][2], xC[2][2], C[2][2];   // [tile][tt]
  int cur = 0;
  const int nst = HASNEXT ? 15 : 13;
  const int slotSeq[15] = {0,1,2,3,4,5,6,7,8,9,10,
                           HASNEXT?13:11, HASNEXT?14:12, 11, 12};
  bfrag Bb[8];

  if (tid < 128){
    biasS[0*128+tid]  = rib1[tid];
    biasS[1*128+tid]  = rib1[128+tid];
    biasS[2*128+tid]  = rib1[256+tid];
    biasS[3*128+tid]  = rib2[tid];
    biasS[4*128+tid]  = rib2[128+tid];
    biasS[5*128+tid]  = rib2[256+tid];
    biasS[6*128+tid]  = db[tid];
    biasS[7*128+tid]  = u[tid];
    biasS[8*128+tid]  = rab1[tid];
    biasS[9*128+tid]  = rab1[128+tid];
    biasS[10*128+tid] = rab2[tid];
    biasS[11*128+tid] = rab2[128+tid];
    biasS[12*128+tid] = rob1[tid];
    biasS[13*128+tid] = rob2[tid];
    biasS[14*128+tid] = biN[tid];
    biasS[15*128+tid] = bjN[tid];
  }
  int rr[2][4];
  #pragma unroll
  for (int T = 0; T < 2; ++T)
    #pragma unroll
    for (int r = 0; r < 4; ++r){
      int row = rbase + T*16 + q*4 + r;
      rr[T][r] = (row < N) ? row : (N-1);
    }
  // preload x rows (used at stage 6)
  float xrow[2][2][4];
  #pragma unroll
  for (int T = 0; T < 2; ++T)
    #pragma unroll
    for (int tt = 0; tt < 2; ++tt){
      int c = (w*2+tt)*16 + m;
      #pragma unroll
      for (int r = 0; r < 4; ++r)
        xrow[T][tt][r] = x_g[(size_t)rr[T][r]*128 + c];
    }
  // S0: load m -> mC; tiles[0] = act(m)
  #pragma unroll
  for (int T = 0; T < 2; ++T)
    #pragma unroll
    for (int tt = 0; tt < 2; ++tt){
      int c = (w*2+tt)*16 + m;
      #pragma unroll
      for (int r = 0; r < 4; ++r){
        float v = m_g[(size_t)rr[T][r]*128 + c];
        mC[T][tt][r] = v;
        tiles[0][(T*16 + q*4 + r)*136 + c] = f2b(actf(v));
      }
    }
  #pragma unroll
  for (int s = 0; s < nst; ++s){
    __syncthreads();
    loadB8(WBb + (size_t)slotSeq[s]*16384, w, l, Bb);
    mmB(&tiles[cur][0],        Bb, l, C[0]);
    mmB(&tiles[cur][16*136],   Bb, l, C[1]);
    if (HASNEXT && s == 11){            // WiN -> m_g for next block
      #pragma unroll
      for (int T = 0; T < 2; ++T)
        #pragma unroll
        for (int tt = 0; tt < 2; ++tt){
          int c = (w*2+tt)*16 + m;
          float bb = biasS[14*128 + c];
          #pragma unroll
          for (int r = 0; r < 4; ++r){
            int row = rbase + T*16 + q*4 + r;
            if (row < N) m_g[(size_t)row*128 + c] = actf(C[T][tt][r] + bb);
          }
        }
    } else if (HASNEXT && s == 12){     // WjN -> xjb for next block
      #pragma unroll
      for (int T = 0; T < 2; ++T)
        #pragma unroll
        for (int tt = 0; tt < 2; ++tt){
          int c = (w*2+tt)*16 + m;
          float bb = biasS[15*128 + c];
          #pragma unroll
          for (int r = 0; r < 4; ++r){
            int row = rbase + T*16 + q*4 + r;
            if (row < N) xjb_g[(size_t)row*128 + c] = actf(C[T][tt][r] + bb);
          }
        }
    } else if (s == 6){                 // x-update
      #pragma unroll
      for (int T = 0; T < 2; ++T)
        #pragma unroll
        for (int tt = 0; tt < 2; ++tt){
          int c = (w*2+tt)*16 + m;
          float uu = biasS[7*128 + c], bb = biasS[6*128 + c];
          #pragma unroll
          for (int r = 0; r < 4; ++r){
            float nv = uu*xrow[T][tt][r] + C[T][tt][r] + bb;
            xC[T][tt][r] = nv;
            tiles[1-cur][(T*16 + q*4 + r)*136 + c] = f2b(actf(nv));
          }
        }
      cur ^= 1;
    } else if (s == 1 || s == 3 || s == 5){   // m-residual close
      #pragma unroll
      for (int T = 0; T < 2; ++T)
        #pragma unroll
        for (int tt = 0; tt < 2; ++tt){
          int c = (w*2+tt)*16 + m;
          float bb = biasS[(3 + (s>>1))*128 + c];
          #pragma unroll
          for (int r = 0; r < 4; ++r){
            float nv = mC[T][tt][r] + C[T][tt][r] + bb;
            mC[T][tt][r] = nv;
            tiles[1-cur][(T*16 + q*4 + r)*136 + c] = f2b(actf(nv));
          }
        }
      cur ^= 1;
    } else if (s == 8 || s == 10){            // x-residual close
      #pragma unroll
      for (int T = 0; T < 2; ++T)
        #pragma unroll
        for (int tt = 0; tt < 2; ++tt){
          int c = (w*2+tt)*16 + m;
          float bb = biasS[(10 + ((s-8)>>1))*128 + c];
          #pragma unroll
          for (int r = 0; r < 4; ++r){
            float nv = xC[T][tt][r] + C[T][tt][r] + bb;
            xC[T][tt][r] = nv;
            tiles[1-cur][(T*16 + q*4 + r)*136 + c] = f2b(actf(nv));
            if (HASNEXT && s == 10){
              int row = rbase + T*16 + q*4 + r;
              if (row < N) x_g[(size_t)row*128 + c] = nv;
            }
          }
        }
      cur ^= 1;
    } else if ((HASNEXT && s == 14) || (!HASNEXT && s == 12)){  // o = x + h@roW2 + b
      #pragma unroll
      for (int T = 0; T < 2; ++T)
        #pragma unroll
        for (int tt = 0; tt < 2; ++tt){
          int c = (w*2+tt)*16 + m;
          float bb = biasS[13*128 + c];
          #pragma unroll
          for (int r = 0; r < 4; ++r){
            float ov = xC[T][tt][r] + C[T][tt][r] + bb;
            tiles[1-cur][(T*16 + q*4 + r)*136 + c] = f2b(actf(ov));
          }
        }
      cur ^= 1;
    } else {                                  // act-only stages
      int bidx = (s==0)?0:(s==2)?1:(s==4)?2:(s==7)?8:(s==9)?9:12;
      #pragma unroll
      for (int T = 0; T < 2; ++T)
        #pragma unroll
        for (int tt = 0; tt < 2; ++tt){
          int c = (w*2+tt)*16 + m;
          float bb = biasS[bidx*128 + c];
          #pragma unroll
          for (int r = 0; r < 4; ++r)
            tiles[1-cur][(T*16 + q*4 + r)*136 + c] = f2b(actf(C[T][tt][r] + bb));
        }
      cur ^= 1;
    }
  }
  // head: waves 0/1 handle tiles 0/1 in parallel
  __syncthreads();
  if (w < 2){
    const unsigned short* tp = &tiles[cur][0] + w*16*136;
    bfrag A[4];
    #pragma unroll
    for (int k0 = 0; k0 < 4; ++k0)
      A[k0] = *(const bfrag*)(tp + m*136 + k0*32 + q*8);
    ffrag Ch = {0.f,0.f,0.f,0.f};
    #pragma unroll
    for (int k0 = 0; k0 < 4; ++k0){
      bfrag B = *(const bfrag*)(outWBb + (size_t)(k0*64 + l)*8);
      Ch = __builtin_amdgcn_mfma_f32_16x16x32_bf16(A[k0], B, Ch, 0, 0, 0);
    }
    int col = m;
    if (col < 2){
      float tpv = 0.f;
      #pragma unroll
      for (int r = 0; r < 4; ++r){
        int row = rbase + w*16 + q*4 + r;
        if (row < N){
          float val = Ch[r];
          if (col == 0) Ea[row] += val; else Qa[row] += val;
          float sq = val*val;
          if (NH){
            float lastv = last2[row*2 + col];
            tpv += sq/(sq + lastv + 1e-7f);
          }
          last2[row*2 + col] = sq;
        }
      }
      if (NH) unsafeAtomicAdd(nh, tpv);
    }
  }
}

__global__ __launch_bounds__(256) void k_final(
    const int* __restrict__ Z, const float* __restrict__ Ea, const float* __restrict__ Qa,
    const float* __restrict__ Es, const float* __restrict__ Eh,
    const float* __restrict__ Qs, const float* __restrict__ Qh,
    const float* __restrict__ nh, float* __restrict__ out, int N, int P){
  int n = blockIdx.x*256 + threadIdx.x;
  if (n < N){
    int z = Z[n];
    out[n]   = Es[z]*Ea[n] + Eh[z];
    out[N+n] = Qs[z]*Qa[n] + Qh[z];
  }
  if (blockIdx.x == 0 && threadIdx.x == 0)
    out[(size_t)2*N + P] = nh[0] / (2.f * (float)N);
}

extern "C" void kernel_launch(void* const* d_in, const int* in_sizes, int n_in,
                              void* d_out, int out_size, void* d_ws, size_t ws_size,
                              hipStream_t stream){
  const int N = in_sizes[0];
  const int P = in_sizes[2];
  const int F = 128;

  const int* Z      = (const int*)d_in[0];
  const float* R    = (const float*)d_in[1];
  const int* idx_i  = (const int*)d_in[2];
  const int* idx_j  = (const int*)d_in[3];
  const float* emb  = (const float*)d_in[4];
  const float* cent = (const float*)d_in[5];
  const float* wid  = (const float*)d_in[6];
  const float* k2f  = (const float*)d_in[7];
  const float* Wi   = (const float*)d_in[8];  const float* bi   = (const float*)d_in[9];
  const float* Wj   = (const float*)d_in[10]; const float* bj   = (const float*)d_in[11];
  const float* riW1 = (const float*)d_in[12]; const float* rib1 = (const float*)d_in[13];
  const float* riW2 = (const float*)d_in[14]; const float* rib2 = (const float*)d_in[15];
  const float* dWp  = (const float*)d_in[16]; const float* dbp  = (const float*)d_in[17];
  const float* u    = (const float*)d_in[18];
  const float* raW1 = (const float*)d_in[19]; const float* rab1 = (const float*)d_in[20];
  const float* raW2 = (const float*)d_in[21]; const float* rab2 = (const float*)d_in[22];
  const float* roW1 = (const float*)d_in[23]; const float* rob1 = (const float*)d_in[24];
  const float* roW2 = (const float*)d_in[25]; const float* rob2 = (const float*)d_in[26];
  const float* outW = (const float*)d_in[27];
  const float* Es   = (const float*)d_in[28]; const float* Eh   = (const float*)d_in[29];
  const float* Qs   = (const float*)d_in[30]; const float* Qh   = (const float*)d_in[31];

  char* ws = (char*)d_ws;
  size_t off = 0;
  float* DijF  = (float*)(ws + off); off += (size_t)P*4;
  float* D_s   = (float*)(ws + off); off += (size_t)P*4;
  int*   i_s   = (int*)  (ws + off); off += (size_t)P*4;
  int*   j_s   = (int*)  (ws + off); off += (size_t)P*4;
  unsigned short* rbf_s = (unsigned short*)(ws + off); off += (size_t)P*64*2;
  unsigned short* k2fP  = (unsigned short*)(ws + off); off += (size_t)5*16*64*8*2;
  unsigned short* WBall = (unsigned short*)(ws + off); off += (size_t)75*16384*2;
  unsigned short* outWB = (unsigned short*)(ws + off); off += (size_t)5*2048*2;
  float* x     = (float*)(ws + off); off += (size_t)N*F*4;
  float* xjb   = (float*)(ws + off); off += (size_t)N*F*4;
  float* m     = (float*)(ws + off); off += (size_t)N*F*4;
  float* last2 = (float*)(ws + off); off += (size_t)N*2*4;
  float* Ea    = (float*)(ws + off); off += (size_t)N*4;   // zero region start
  float* Qa    = (float*)(ws + off); off += (size_t)N*4;
  float* nh    = (float*)(ws + off); off += 256;
  int*   counts= (int*)  (ws + off); off += (size_t)N*4;   // zero region end
  int*   starts= (int*)  (ws + off); off += (size_t)(N+1)*4;
  int*   cursor= (int*)  (ws + off); off += (size_t)N*4;
  int*   locEx = (int*)  (ws + off); off += (size_t)N*4;
  int*   bsum  = (int*)  (ws + off); off += 64*4;
  int*   boff  = (int*)  (ws + off); off += 68*4;

  float* outF = (float*)d_out;
  float* Dout = outF + (size_t)2*N;

  const int nb = (N + 255)/256;   // 40
  const int nzero = 3*N + 64;
  k_zero<<<dim3((nzero+255)/256), dim3(256), 0, stream>>>(Ea, nzero);
  k_dij_count<<<dim3((P+255)/256), dim3(256), 0, stream>>>(R, idx_i, idx_j, DijF, Dout, counts, P);
  k_scanA<<<dim3(nb), dim3(256), 0, stream>>>(counts, locEx, bsum, N);
  k_scanB<<<dim3(1), dim3(64), 0, stream>>>(bsum, boff, nb);
  k_scanC<<<dim3(nb), dim3(256), 0, stream>>>(locEx, boff, starts, cursor, N, nb);
  k_scatter<<<dim3((P+255)/256), dim3(256), 0, stream>>>(idx_i, idx_j, DijF, cursor, i_s, j_s, D_s, P);
  k_rbf<<<dim3((P*64+255)/256), dim3(256), 0, stream>>>(D_s, cent, wid, rbf_s, P);
  k_prep<<<dim3(20), dim3(256), 0, stream>>>(k2f, k2fP);
  k_prepAll<<<dim3((75*2048+255)/256), dim3(256), 0, stream>>>(riW1, riW2, dWp, raW1, raW2,
                                                               roW1, roW2, Wi, Wj, WBall);
  k_prepO<<<dim3(5), dim3(256), 0, stream>>>(outW, outWB);

  const int G16 = (N + 15)/16;   // 625
  const int G32 = (N + 31)/32;   // 313
  k_phase1m<<<dim3(G16), dim3(128), 0, stream>>>(Z, emb, WBall + (size_t)4*15*16384,
                                                 bi, bj, x, m, xjb, N);

  const int pmg = (P + 511)/512;
  for (int b = 0; b < 5; ++b){
    k_pairmsg2<<<dim3(pmg), dim3(256), 0, stream>>>(rbf_s, k2fP + (size_t)b*16*64*8,
                                                    i_s, j_s, xjb, m, P);
    const unsigned short* WBb = WBall + (size_t)b*15*16384;
    const float* a_rib1 = rib1 + (size_t)b*3*F;
    const float* a_rib2 = rib2 + (size_t)b*3*F;
    const float* a_db   = dbp  + (size_t)b*F;
    const float* a_u    = u    + (size_t)b*F;
    const float* a_rab1 = rab1 + (size_t)b*2*F;
    const float* a_rab2 = rab2 + (size_t)b*2*F;
    const float* a_rob1 = rob1 + (size_t)b*F;
    const float* a_rob2 = rob2 + (size_t)b*F;
    int bn = (b < 4) ? (b+1) : 0;
    const float* a_biN = bi + (size_t)bn*F;
    const float* a_bjN = bj + (size_t)bn*F;
    const unsigned short* oWB = outWB + (size_t)b*2048;
    if (b == 0){
      k_phase2m<1,0><<<dim3(G32), dim3(256), 0, stream>>>(m, x, xjb, WBb,
        a_rib1, a_rib2, a_db, a_u, a_rab1, a_rab2, a_rob1, a_rob2,
        a_biN, a_bjN, oWB, Ea, Qa, last2, nh, N);
    } else if (b < 4){
      k_phase2m<1,1><<<dim3(G32), dim3(256), 0, stream>>>(m, x, xjb, WBb,
        a_rib1, a_rib2, a_db, a_u, a_rab1, a_rab2, a_rob1, a_rob2,
        a_biN, a_bjN, oWB, Ea, Qa, last2, nh, N);
    } else {
      k_phase2m<0,1><<<dim3(G32), dim3(256), 0, stream>>>(m, x, xjb, WBb,
        a_rib1, a_rib2, a_db, a_u, a_rab1, a_rab2, a_rob1, a_rob2,
        a_biN, a_bjN, oWB, Ea, Qa, last2, nh, N);
    }
  }
  k_final<<<dim3((N+255)/256), dim3(256), 0, stream>>>(Z, Ea, Qa, Es, Eh, Qs, Qh, nh, outF, N, P);
}

// Round 12
// 548.831 us; speedup vs baseline: 1.0604x; 1.0604x over previous
//
#include <hip/hip_runtime.h>

typedef __attribute__((ext_vector_type(8))) short bfrag;   // 8 bf16 (4 VGPRs)
typedef __attribute__((ext_vector_type(4))) float ffrag;   // 4 fp32

__device__ __forceinline__ unsigned short f2b(float f){
  unsigned int u = __float_as_uint(f);
  return (unsigned short)((u + 0x7FFFu + ((u >> 16) & 1u)) >> 16);
}
// shifted softplus via v_exp/v_log (both base-2 on gfx950)
__device__ __forceinline__ float actf(float v){
  float e = __builtin_amdgcn_exp2f(-fabsf(v)*1.44269504088896341f);
  return fmaxf(v, 0.f) + __builtin_amdgcn_logf(1.f + e)*0.69314718055994531f - 0.69314718055994531f;
}

// ---------- small utility kernels ----------
__global__ __launch_bounds__(256) void k_zero(float* p, int n){
  int i = blockIdx.x*256 + threadIdx.x;
  if (i < n) p[i] = 0.f;
}

__global__ __launch_bounds__(256) void k_dij_count(
    const float* __restrict__ R, const int* __restrict__ idx_i, const int* __restrict__ idx_j,
    float* __restrict__ DijF, float* __restrict__ Dout, int* __restrict__ counts, int P){
  int p = blockIdx.x*256 + threadIdx.x;
  if (p >= P) return;
  int i = idx_i[p], j = idx_j[p];
  float dx = R[i*3+0] - R[j*3+0];
  float dy = R[i*3+1] - R[j*3+1];
  float dz = R[i*3+2] - R[j*3+2];
  float D = sqrtf(fmaxf(dx*dx + dy*dy + dz*dz, 0.f));
  DijF[p] = D;
  Dout[p] = D;
  atomicAdd(&counts[i], 1);
}

// hierarchical scan
__global__ __launch_bounds__(256) void k_scanA(const int* __restrict__ counts,
    int* __restrict__ locEx, int* __restrict__ bsum, int N){
  __shared__ int buf[256];
  int tid = threadIdx.x, idx = blockIdx.x*256 + tid;
  int v = (idx < N) ? counts[idx] : 0;
  buf[tid] = v;
  __syncthreads();
  for (int off = 1; off < 256; off <<= 1){
    int t = (tid >= off) ? buf[tid-off] : 0;
    __syncthreads();
    buf[tid] += t;
    __syncthreads();
  }
  if (idx < N) locEx[idx] = buf[tid] - v;
  if (tid == 255) bsum[blockIdx.x] = buf[255];
}
__global__ __launch_bounds__(64) void k_scanB(int* __restrict__ bsum,
    int* __restrict__ boff, int nb){
  if (threadIdx.x == 0){
    int acc = 0;
    for (int i = 0; i < nb; ++i){ boff[i] = acc; acc += bsum[i]; }
    boff[nb] = acc;
  }
}
__global__ __launch_bounds__(256) void k_scanC(const int* __restrict__ locEx,
    const int* __restrict__ boff, int* __restrict__ starts, int* __restrict__ cursor,
    int N, int nb){
  int idx = blockIdx.x*256 + threadIdx.x;
  if (idx < N){
    int s = locEx[idx] + boff[blockIdx.x];
    starts[idx] = s; cursor[idx] = s;
  }
  if (idx == 0) starts[N] = boff[nb];
}

__global__ __launch_bounds__(256) void k_scatter(const int* __restrict__ idx_i,
    const int* __restrict__ idx_j, const float* __restrict__ DijF,
    int* __restrict__ cursor, int* __restrict__ i_s, int* __restrict__ j_s,
    float* __restrict__ D_s, int P){
  int p = blockIdx.x*256 + threadIdx.x;
  if (p >= P) return;
  int i = idx_i[p];
  int pos = atomicAdd(&cursor[i], 1);
  i_s[pos] = i;
  j_s[pos] = idx_j[p];
  D_s[pos] = DijF[p];
}

__global__ __launch_bounds__(256) void k_rbf(
    const float* __restrict__ D_s, const float* __restrict__ cent, const float* __restrict__ wid,
    unsigned short* __restrict__ rbf_s, int P){
  int gid = blockIdx.x*256 + threadIdx.x;
  if (gid >= P*64) return;
  int t = gid >> 6, k = gid & 63;
  float D = D_s[t];
  float xc = D * 0.1f;
  float cut = 0.f;
  if (xc < 1.f){
    float x3 = xc*xc*xc, x4 = x3*xc, x5 = x4*xc;
    cut = 1.f - 6.f*x5 + 15.f*x4 - 10.f*x3;
  }
  float tt = expf(-D) - cent[k];
  rbf_s[gid] = f2b(cut * expf(-wid[k]*tt*tt));
}

// k2f B-frag prep -- unchanged, HW-verified
__global__ __launch_bounds__(256) void k_prep(const float* __restrict__ k2f,
    unsigned short* __restrict__ k2fP){
  int gid = blockIdx.x*256 + threadIdx.x;
  if (gid >= 5120) return;
  int l = gid & 63, fr = (gid >> 6) & 15, b = gid >> 10;
  int tile = fr >> 1, kh = fr & 1;
  const float* src = k2f + (size_t)b*64*128;
  int n = tile*16 + (l & 15);
  int kbase = kh*32 + (l >> 4)*8;
  ushort4 o0, o1;
  o0.x = f2b(src[(kbase+0)*128+n]); o0.y = f2b(src[(kbase+1)*128+n]);
  o0.z = f2b(src[(kbase+2)*128+n]); o0.w = f2b(src[(kbase+3)*128+n]);
  o1.x = f2b(src[(kbase+4)*128+n]); o1.y = f2b(src[(kbase+5)*128+n]);
  o1.z = f2b(src[(kbase+6)*128+n]); o1.w = f2b(src[(kbase+7)*128+n]);
  ushort4* dst = (ushort4*)(k2fP + (size_t)gid*8);
  dst[0] = o0; dst[1] = o1;
}

// ALL 75 weight matrices repacked in ONE launch (mapping as round 9)
__global__ __launch_bounds__(256) void k_prepAll(
    const float* __restrict__ riW1, const float* __restrict__ riW2,
    const float* __restrict__ dW,   const float* __restrict__ raW1,
    const float* __restrict__ raW2, const float* __restrict__ roW1,
    const float* __restrict__ roW2, const float* __restrict__ Wi,
    const float* __restrict__ Wj,   unsigned short* __restrict__ WBall){
  int gid = blockIdx.x*256 + threadIdx.x;
  if (gid >= 75*2048) return;
  int i = gid >> 11, r = gid & 2047;
  const float* S;
  int slot;
  if (i < 15)      { S = riW1 + (size_t)i*16384;      slot = (i/3)*15 + 2*(i%3); }
  else if (i < 30) { int j=i-15; S = riW2 + (size_t)j*16384; slot = (j/3)*15 + 2*(j%3) + 1; }
  else if (i < 35) { int j=i-30; S = dW   + (size_t)j*16384; slot = j*15 + 6; }
  else if (i < 45) { int j=i-35; S = raW1 + (size_t)j*16384; slot = (j/2)*15 + 7 + 2*(j%2); }
  else if (i < 55) { int j=i-45; S = raW2 + (size_t)j*16384; slot = (j/2)*15 + 8 + 2*(j%2); }
  else if (i < 60) { int j=i-55; S = roW1 + (size_t)j*16384; slot = j*15 + 11; }
  else if (i < 65) { int j=i-60; S = roW2 + (size_t)j*16384; slot = j*15 + 12; }
  else if (i < 70) { int j=i-65; S = Wi   + (size_t)j*16384; slot = ((j==0)?4:(j-1))*15 + 13; }
  else             { int j=i-70; S = Wj   + (size_t)j*16384; slot = ((j==0)?4:(j-1))*15 + 14; }
  int fr = r >> 6, l = r & 63;
  int T = fr >> 2, k0 = fr & 3;
  int n = T*16 + (l & 15);
  int kbase = k0*32 + (l >> 4)*8;
  unsigned short* D = WBall + ((size_t)slot*2048 + r)*8;
  ushort4 o0, o1;
  o0.x=f2b(S[(kbase+0)*128+n]); o0.y=f2b(S[(kbase+1)*128+n]);
  o0.z=f2b(S[(kbase+2)*128+n]); o0.w=f2b(S[(kbase+3)*128+n]);
  o1.x=f2b(S[(kbase+4)*128+n]); o1.y=f2b(S[(kbase+5)*128+n]);
  o1.z=f2b(S[(kbase+6)*128+n]); o1.w=f2b(S[(kbase+7)*128+n]);
  ((ushort4*)D)[0]=o0; ((ushort4*)D)[1]=o1;
}

// outW[b] [128x2] -> padded B-frags -- unchanged
__global__ __launch_bounds__(256) void k_prepO(const float* __restrict__ outW,
    unsigned short* __restrict__ outWB){
  int gid = blockIdx.x*256 + threadIdx.x;
  if (gid >= 5*256) return;
  int b = gid >> 8, r = gid & 255;
  int l = r & 63;
  int col = l & 15;
  int k0 = r >> 6;
  int kbase = k0*32 + (l >> 4)*8;
  ushort4 o0 = {0,0,0,0}, o1 = {0,0,0,0};
  if (col < 2){
    const float* S = outW + (size_t)b*256;
    o0.x=f2b(S[(kbase+0)*2+col]); o0.y=f2b(S[(kbase+1)*2+col]);
    o0.z=f2b(S[(kbase+2)*2+col]); o0.w=f2b(S[(kbase+3)*2+col]);
    o1.x=f2b(S[(kbase+4)*2+col]); o1.y=f2b(S[(kbase+5)*2+col]);
    o1.z=f2b(S[(kbase+6)*2+col]); o1.w=f2b(S[(kbase+7)*2+col]);
  }
  unsigned short* D = outWB + ((size_t)b*256 + r)*8;
  ((ushort4*)D)[0]=o0; ((ushort4*)D)[1]=o1;
}

// ---------- MFMA tile machinery ----------
// phase1 (2 waves, 4 col-tiles each)
__device__ __forceinline__ void mmtile(const unsigned short* tile,
    const unsigned short* __restrict__ WB, int w, int l, ffrag C[4]){
  int m = l & 15, q = l >> 4;
  bfrag A[4];
  #pragma unroll
  for (int k0 = 0; k0 < 4; ++k0)
    A[k0] = *(const bfrag*)(tile + m*136 + k0*32 + q*8);
  #pragma unroll
  for (int tt = 0; tt < 4; ++tt){
    ffrag c = {0.f,0.f,0.f,0.f};
    const bfrag* bp = (const bfrag*)(WB + (((w*4+tt)*4)*64 + l)*8);
    #pragma unroll
    for (int k0 = 0; k0 < 4; ++k0)
      c = __builtin_amdgcn_mfma_f32_16x16x32_bf16(A[k0], bp[k0*64], c, 0, 0, 0);
    C[tt] = c;
  }
}

// phase2 (8 waves, ONE 16-col tile per wave): 4 B-frags, single 4-MFMA chain
__device__ __forceinline__ void loadB4(const unsigned short* __restrict__ WB,
    int w, int l, bfrag* B){
  #pragma unroll
  for (int k0 = 0; k0 < 4; ++k0)
    B[k0] = *(const bfrag*)(WB + ((size_t)((w*4+k0)*64 + l))*8);
}
__device__ __forceinline__ void mmB1(const unsigned short* tile, const bfrag* B,
    int l, ffrag& C){
  int m = l & 15, q = l >> 4;
  ffrag c = {0.f,0.f,0.f,0.f};
  #pragma unroll
  for (int k0 = 0; k0 < 4; ++k0){
    bfrag A = *(const bfrag*)(tile + m*136 + k0*32 + q*8);
    c = __builtin_amdgcn_mfma_f32_16x16x32_bf16(A, B[k0], c, 0, 0, 0);
  }
  C = c;
}

// phase1: x = emb[Z]; m_g = act(act(x)@Wi0+bi0); xjb = act(act(x)@Wj0+bj0)
__global__ __launch_bounds__(128) void k_phase1m(
    const int* __restrict__ Z, const float* __restrict__ emb,
    const unsigned short* __restrict__ WB45,
    const float* __restrict__ bi0, const float* __restrict__ bj0,
    float* __restrict__ x_g, float* __restrict__ m_g, float* __restrict__ xjb_g, int N){
  __shared__ unsigned short tile[16*136];
  int tid = threadIdx.x, w = tid >> 6, l = tid & 63;
  int m = l & 15, q = l >> 4, rbase = blockIdx.x*16;
  #pragma unroll
  for (int r = 0; r < 4; ++r){
    int row = rbase + q*4 + r;
    int z = Z[row];
    #pragma unroll
    for (int tt = 0; tt < 4; ++tt){
      int c = (w*4+tt)*16 + m;
      float v = emb[(size_t)z*128 + c];
      x_g[(size_t)row*128 + c] = v;
      tile[(q*4+r)*136 + c] = f2b(actf(v));
    }
  }
  __syncthreads();
  ffrag C[4];
  mmtile(tile, WB45 + 13*16384, w, l, C);
  #pragma unroll
  for (int tt = 0; tt < 4; ++tt){
    int c = (w*4+tt)*16 + m;
    float bb = bi0[c];
    #pragma unroll
    for (int r = 0; r < 4; ++r)
      m_g[(size_t)(rbase + q*4 + r)*128 + c] = actf(C[tt][r] + bb);
  }
  mmtile(tile, WB45 + 14*16384, w, l, C);
  #pragma unroll
  for (int tt = 0; tt < 4; ++tt){
    int c = (w*4+tt)*16 + m;
    float bb = bj0[c];
    #pragma unroll
    for (int r = 0; r < 4; ++r)
      xjb_g[(size_t)(rbase + q*4 + r)*128 + c] = actf(C[tt][r] + bb);
  }
}

// MFMA pair-message -- unchanged from round 10 (bench-validated)
__global__ __launch_bounds__(256) void k_pairmsg2(
    const unsigned short* __restrict__ rbf_s, const unsigned short* __restrict__ k2fP,
    const int* __restrict__ i_s, const int* __restrict__ j_s,
    const float* __restrict__ xj, float* __restrict__ m_g, int P){
  __shared__ float G[4][16*130];
  int tid = threadIdx.x, w = tid >> 6, l = tid & 63;
  float* Gw = &G[w][0];
  bfrag B[16];
  #pragma unroll
  for (int t = 0; t < 8; ++t){
    #pragma unroll
    for (int kh = 0; kh < 2; ++kh)
      B[t*2+kh] = *(const bfrag*)(k2fP + (size_t)((t*2+kh)*64 + l)*8);
  }
  int wstart = (blockIdx.x*4 + w)*128;
  if (wstart >= P) return;
  int row16 = l & 15, quad = l >> 4;
  float a0 = 0.f, a1 = 0.f;
  int iCur = -1;
  bfrag A0 = *(const bfrag*)(rbf_s + (size_t)(wstart + row16)*64 + quad*8);
  bfrag A1 = *(const bfrag*)(rbf_s + (size_t)(wstart + row16)*64 + 32 + quad*8);
  int4 iv[4], jv[4];
  #pragma unroll
  for (int g = 0; g < 4; ++g){
    iv[g] = *(const int4*)(i_s + wstart + g*4);
    jv[g] = *(const int4*)(j_s + wstart + g*4);
  }
  #pragma unroll 1
  for (int bi2 = 0; bi2 < 8; ++bi2){
    int bt = wstart + bi2*16;
    const int* ip = (const int*)iv;
    const int* jp = (const int*)jv;
    float2 xv[16];
    #pragma unroll
    for (int k = 0; k < 16; ++k)
      xv[k] = *(const float2*)(xj + (size_t)jp[k]*128 + 2*l);
    #pragma unroll
    for (int t = 0; t < 8; ++t){
      ffrag C = {0.f,0.f,0.f,0.f};
      C = __builtin_amdgcn_mfma_f32_16x16x32_bf16(A0, B[t*2],   C, 0, 0, 0);
      C = __builtin_amdgcn_mfma_f32_16x16x32_bf16(A1, B[t*2+1], C, 0, 0, 0);
      #pragma unroll
      for (int r = 0; r < 4; ++r)
        Gw[(quad*4+r)*130 + t*16 + row16] = C[r];
    }
    bfrag nA0, nA1;
    int4 niv[4], njv[4];
    if (bi2 < 7){
      int btn = bt + 16;
      nA0 = *(const bfrag*)(rbf_s + (size_t)(btn + row16)*64 + quad*8);
      nA1 = *(const bfrag*)(rbf_s + (size_t)(btn + row16)*64 + 32 + quad*8);
      #pragma unroll
      for (int g = 0; g < 4; ++g){
        niv[g] = *(const int4*)(i_s + btn + g*4);
        njv[g] = *(const int4*)(j_s + btn + g*4);
      }
    }
    #pragma unroll
    for (int k = 0; k < 16; ++k){
      int i = ip[k];
      if (i != iCur){
        if (iCur >= 0){
          unsafeAtomicAdd(&m_g[(size_t)iCur*128 + 2*l],     a0);
          unsafeAtomicAdd(&m_g[(size_t)iCur*128 + 2*l + 1], a1);
        }
        iCur = i; a0 = 0.f; a1 = 0.f;
      }
      float g0 = Gw[k*130 + 2*l], g1 = Gw[k*130 + 2*l + 1];
      a0 = fmaf(g0, xv[k].x, a0);
      a1 = fmaf(g1, xv[k].y, a1);
    }
    if (bi2 < 7){
      A0 = nA0; A1 = nA1;
      #pragma unroll
      for (int g = 0; g < 4; ++g){ iv[g] = niv[g]; jv[g] = njv[g]; }
    }
  }
  if (iCur >= 0){
    unsafeAtomicAdd(&m_g[(size_t)iCur*128 + 2*l],     a0);
    unsafeAtomicAdd(&m_g[(size_t)iCur*128 + 2*l + 1], a1);
  }
}

// ---------- phase 2: 8 waves, ONE col-tile per wave, 16-row tile ----------
// W slots: riW1[l]=2l riW2[l]=2l+1 dW=6 raW1=7+2l raW2=8+2l roW1=11 roW2=12 WiN=13 WjN=14
// Stage seq (HASNEXT): 0..10,13,14,11,12 ; (!HASNEXT): 0..10,11,12
// Bias LDS: 0-2 rib1, 3-5 rib2, 6 db, 7 u, 8-9 rab1, 10-11 rab2, 12 rob1, 13 rob2, 14 biN, 15 bjN
template<int HASNEXT, int NH>
__global__ __launch_bounds__(512) void k_phase2m(
    float* __restrict__ m_g, float* __restrict__ x_g, float* __restrict__ xjb_g,
    const unsigned short* __restrict__ WBb,
    const float* __restrict__ rib1, const float* __restrict__ rib2,
    const float* __restrict__ db, const float* __restrict__ u,
    const float* __restrict__ rab1, const float* __restrict__ rab2,
    const float* __restrict__ rob1, const float* __restrict__ rob2,
    const float* __restrict__ biN, const float* __restrict__ bjN,
    const unsigned short* __restrict__ outWBb,
    float* __restrict__ Ea, float* __restrict__ Qa,
    float* __restrict__ last2, float* __restrict__ nh, int N){
  __shared__ unsigned short tiles[2][16*136];
  __shared__ float biasS[16*128];
  int tid = threadIdx.x, w = tid >> 6, l = tid & 63;
  int m = l & 15, q = l >> 4, rbase = blockIdx.x*16;
  int c = w*16 + m;                 // this wave's column
  ffrag mC, xC, C;
  int cur = 0;
  const int nst = HASNEXT ? 15 : 13;
  const int slotSeq[15] = {0,1,2,3,4,5,6,7,8,9,10,
                           HASNEXT?13:11, HASNEXT?14:12, 11, 12};
  bfrag Bb[4];

  if (tid < 128){
    biasS[0*128+tid]  = rib1[tid];
    biasS[1*128+tid]  = rib1[128+tid];
    biasS[2*128+tid]  = rib1[256+tid];
    biasS[3*128+tid]  = rib2[tid];
    biasS[4*128+tid]  = rib2[128+tid];
    biasS[5*128+tid]  = rib2[256+tid];
    biasS[6*128+tid]  = db[tid];
    biasS[7*128+tid]  = u[tid];
    biasS[8*128+tid]  = rab1[tid];
    biasS[9*128+tid]  = rab1[128+tid];
    biasS[10*128+tid] = rab2[tid];
    biasS[11*128+tid] = rab2[128+tid];
    biasS[12*128+tid] = rob1[tid];
    biasS[13*128+tid] = rob2[tid];
    biasS[14*128+tid] = biN[tid];
    biasS[15*128+tid] = bjN[tid];
  }
  // preload x rows (used at stage 6)
  float xrow[4];
  #pragma unroll
  for (int r = 0; r < 4; ++r)
    xrow[r] = x_g[(size_t)(rbase + q*4 + r)*128 + c];
  // S0: load m -> mC; tiles[0] = act(m)
  #pragma unroll
  for (int r = 0; r < 4; ++r){
    float v = m_g[(size_t)(rbase + q*4 + r)*128 + c];
    mC[r] = v;
    tiles[0][(q*4+r)*136 + c] = f2b(actf(v));
  }
  #pragma unroll
  for (int s = 0; s < nst; ++s){
    __syncthreads();
    loadB4(WBb + (size_t)slotSeq[s]*16384, w, l, Bb);
    mmB1(tiles[cur], Bb, l, C);
    if (HASNEXT && s == 11){            // WiN -> m_g for next block
      float bb = biasS[14*128 + c];
      #pragma unroll
      for (int r = 0; r < 4; ++r)
        m_g[(size_t)(rbase + q*4 + r)*128 + c] = actf(C[r] + bb);
    } else if (HASNEXT && s == 12){     // WjN -> xjb for next block
      float bb = biasS[15*128 + c];
      #pragma unroll
      for (int r = 0; r < 4; ++r)
        xjb_g[(size_t)(rbase + q*4 + r)*128 + c] = actf(C[r] + bb);
    } else if (s == 6){                 // x-update
      float uu = biasS[7*128 + c], bb = biasS[6*128 + c];
      #pragma unroll
      for (int r = 0; r < 4; ++r){
        float nv = uu*xrow[r] + C[r] + bb;
        xC[r] = nv;
        tiles[1-cur][(q*4+r)*136 + c] = f2b(actf(nv));
      }
      cur ^= 1;
    } else if (s == 1 || s == 3 || s == 5){   // m-residual close
      float bb = biasS[(3 + (s>>1))*128 + c];
      #pragma unroll
      for (int r = 0; r < 4; ++r){
        float nv = mC[r] + C[r] + bb;
        mC[r] = nv;
        tiles[1-cur][(q*4+r)*136 + c] = f2b(actf(nv));
      }
      cur ^= 1;
    } else if (s == 8 || s == 10){            // x-residual close
      float bb = biasS[(10 + ((s-8)>>1))*128 + c];
      #pragma unroll
      for (int r = 0; r < 4; ++r){
        float nv = xC[r] + C[r] + bb;
        xC[r] = nv;
        tiles[1-cur][(q*4+r)*136 + c] = f2b(actf(nv));
        if (HASNEXT && s == 10)
          x_g[(size_t)(rbase + q*4 + r)*128 + c] = nv;
      }
      cur ^= 1;
    } else if ((HASNEXT && s == 14) || (!HASNEXT && s == 12)){  // o = x + h@roW2 + b
      float bb = biasS[13*128 + c];
      #pragma unroll
      for (int r = 0; r < 4; ++r){
        float ov = xC[r] + C[r] + bb;
        tiles[1-cur][(q*4+r)*136 + c] = f2b(actf(ov));
      }
      cur ^= 1;
    } else {                                  // act-only stages
      int bidx = (s==0)?0:(s==2)?1:(s==4)?2:(s==7)?8:(s==9)?9:12;
      float bb = biasS[bidx*128 + c];
      #pragma unroll
      for (int r = 0; r < 4; ++r)
        tiles[1-cur][(q*4+r)*136 + c] = f2b(actf(C[r] + bb));
      cur ^= 1;
    }
  }
  // head: out = act(o) @ outW (padded to 16 cols), wave 0 only
  __syncthreads();
  if (w == 0){
    bfrag A[4];
    #pragma unroll
    for (int k0 = 0; k0 < 4; ++k0)
      A[k0] = *(const bfrag*)(&tiles[cur][0] + m*136 + k0*32 + q*8);
    ffrag Ch = {0.f,0.f,0.f,0.f};
    #pragma unroll
    for (int k0 = 0; k0 < 4; ++k0){
      bfrag B = *(const bfrag*)(outWBb + (size_t)(k0*64 + l)*8);
      Ch = __builtin_amdgcn_mfma_f32_16x16x32_bf16(A[k0], B, Ch, 0, 0, 0);
    }
    int col = m;
    if (col < 2){
      float tp = 0.f;
      #pragma unroll
      for (int r = 0; r < 4; ++r){
        int row = rbase + q*4 + r;
        float val = Ch[r];
        if (col == 0) Ea[row] += val; else Qa[row] += val;
        float sq = val*val;
        if (NH){
          float lastv = last2[row*2 + col];
          tp += sq/(sq + lastv + 1e-7f);
        }
        last2[row*2 + col] = sq;
      }
      if (NH) unsafeAtomicAdd(nh, tp);
    }
  }
}

__global__ __launch_bounds__(256) void k_final(
    const int* __restrict__ Z, const float* __restrict__ Ea, const float* __restrict__ Qa,
    const float* __restrict__ Es, const float* __restrict__ Eh,
    const float* __restrict__ Qs, const float* __restrict__ Qh,
    const float* __restrict__ nh, float* __restrict__ out, int N, int P){
  int n = blockIdx.x*256 + threadIdx.x;
  if (n < N){
    int z = Z[n];
    out[n]   = Es[z]*Ea[n] + Eh[z];
    out[N+n] = Qs[z]*Qa[n] + Qh[z];
  }
  if (blockIdx.x == 0 && threadIdx.x == 0)
    out[(size_t)2*N + P] = nh[0] / (2.f * (float)N);
}

extern "C" void kernel_launch(void* const* d_in, const int* in_sizes, int n_in,
                              void* d_out, int out_size, void* d_ws, size_t ws_size,
                              hipStream_t stream){
  const int N = in_sizes[0];
  const int P = in_sizes[2];
  const int F = 128;

  const int* Z      = (const int*)d_in[0];
  const float* R    = (const float*)d_in[1];
  const int* idx_i  = (const int*)d_in[2];
  const int* idx_j  = (const int*)d_in[3];
  const float* emb  = (const float*)d_in[4];
  const float* cent = (const float*)d_in[5];
  const float* wid  = (const float*)d_in[6];
  const float* k2f  = (const float*)d_in[7];
  const float* Wi   = (const float*)d_in[8];  const float* bi   = (const float*)d_in[9];
  const float* Wj   = (const float*)d_in[10]; const float* bj   = (const float*)d_in[11];
  const float* riW1 = (const float*)d_in[12]; const float* rib1 = (const float*)d_in[13];
  const float* riW2 = (const float*)d_in[14]; const float* rib2 = (const float*)d_in[15];
  const float* dWp  = (const float*)d_in[16]; const float* dbp  = (const float*)d_in[17];
  const float* u    = (const float*)d_in[18];
  const float* raW1 = (const float*)d_in[19]; const float* rab1 = (const float*)d_in[20];
  const float* raW2 = (const float*)d_in[21]; const float* rab2 = (const float*)d_in[22];
  const float* roW1 = (const float*)d_in[23]; const float* rob1 = (const float*)d_in[24];
  const float* roW2 = (const float*)d_in[25]; const float* rob2 = (const float*)d_in[26];
  const float* outW = (const float*)d_in[27];
  const float* Es   = (const float*)d_in[28]; const float* Eh   = (const float*)d_in[29];
  const float* Qs   = (const float*)d_in[30]; const float* Qh   = (const float*)d_in[31];

  char* ws = (char*)d_ws;
  size_t off = 0;
  float* DijF  = (float*)(ws + off); off += (size_t)P*4;
  float* D_s   = (float*)(ws + off); off += (size_t)P*4;
  int*   i_s   = (int*)  (ws + off); off += (size_t)P*4;
  int*   j_s   = (int*)  (ws + off); off += (size_t)P*4;
  unsigned short* rbf_s = (unsigned short*)(ws + off); off += (size_t)P*64*2;
  unsigned short* k2fP  = (unsigned short*)(ws + off); off += (size_t)5*16*64*8*2;
  unsigned short* WBall = (unsigned short*)(ws + off); off += (size_t)75*16384*2;
  unsigned short* outWB = (unsigned short*)(ws + off); off += (size_t)5*2048*2;
  float* x     = (float*)(ws + off); off += (size_t)N*F*4;
  float* xjb   = (float*)(ws + off); off += (size_t)N*F*4;
  float* m     = (float*)(ws + off); off += (size_t)N*F*4;
  float* last2 = (float*)(ws + off); off += (size_t)N*2*4;
  float* Ea    = (float*)(ws + off); off += (size_t)N*4;   // zero region start
  float* Qa    = (float*)(ws + off); off += (size_t)N*4;
  float* nh    = (float*)(ws + off); off += 256;
  int*   counts= (int*)  (ws + off); off += (size_t)N*4;   // zero region end
  int*   starts= (int*)  (ws + off); off += (size_t)(N+1)*4;
  int*   cursor= (int*)  (ws + off); off += (size_t)N*4;
  int*   locEx = (int*)  (ws + off); off += (size_t)N*4;
  int*   bsum  = (int*)  (ws + off); off += 64*4;
  int*   boff  = (int*)  (ws + off); off += 68*4;

  float* outF = (float*)d_out;
  float* Dout = outF + (size_t)2*N;

  const int nb = (N + 255)/256;   // 40
  const int nzero = 3*N + 64;
  k_zero<<<dim3((nzero+255)/256), dim3(256), 0, stream>>>(Ea, nzero);
  k_dij_count<<<dim3((P+255)/256), dim3(256), 0, stream>>>(R, idx_i, idx_j, DijF, Dout, counts, P);
  k_scanA<<<dim3(nb), dim3(256), 0, stream>>>(counts, locEx, bsum, N);
  k_scanB<<<dim3(1), dim3(64), 0, stream>>>(bsum, boff, nb);
  k_scanC<<<dim3(nb), dim3(256), 0, stream>>>(locEx, boff, starts, cursor, N, nb);
  k_scatter<<<dim3((P+255)/256), dim3(256), 0, stream>>>(idx_i, idx_j, DijF, cursor, i_s, j_s, D_s, P);
  k_rbf<<<dim3((P*64+255)/256), dim3(256), 0, stream>>>(D_s, cent, wid, rbf_s, P);
  k_prep<<<dim3(20), dim3(256), 0, stream>>>(k2f, k2fP);
  k_prepAll<<<dim3((75*2048+255)/256), dim3(256), 0, stream>>>(riW1, riW2, dWp, raW1, raW2,
                                                               roW1, roW2, Wi, Wj, WBall);
  k_prepO<<<dim3(5), dim3(256), 0, stream>>>(outW, outWB);

  const int G16 = (N + 15)/16;   // 625
  k_phase1m<<<dim3(G16), dim3(128), 0, stream>>>(Z, emb, WBall + (size_t)4*15*16384,
                                                 bi, bj, x, m, xjb, N);

  const int pmg = (P + 511)/512;
  for (int b = 0; b < 5; ++b){
    k_pairmsg2<<<dim3(pmg), dim3(256), 0, stream>>>(rbf_s, k2fP + (size_t)b*16*64*8,
                                                    i_s, j_s, xjb, m, P);
    const unsigned short* WBb = WBall + (size_t)b*15*16384;
    const float* a_rib1 = rib1 + (size_t)b*3*F;
    const float* a_rib2 = rib2 + (size_t)b*3*F;
    const float* a_db   = dbp  + (size_t)b*F;
    const float* a_u    = u    + (size_t)b*F;
    const float* a_rab1 = rab1 + (size_t)b*2*F;
    const float* a_rab2 = rab2 + (size_t)b*2*F;
    const float* a_rob1 = rob1 + (size_t)b*F;
    const float* a_rob2 = rob2 + (size_t)b*F;
    int bn = (b < 4) ? (b+1) : 0;
    const float* a_biN = bi + (size_t)bn*F;
    const float* a_bjN = bj + (size_t)bn*F;
    const unsigned short* oWB = outWB + (size_t)b*2048;
    if (b == 0){
      k_phase2m<1,0><<<dim3(G16), dim3(512), 0, stream>>>(m, x, xjb, WBb,
        a_rib1, a_rib2, a_db, a_u, a_rab1, a_rab2, a_rob1, a_rob2,
        a_biN, a_bjN, oWB, Ea, Qa, last2, nh, N);
    } else if (b < 4){
      k_phase2m<1,1><<<dim3(G16), dim3(512), 0, stream>>>(m, x, xjb, WBb,
        a_rib1, a_rib2, a_db, a_u, a_rab1, a_rab2, a_rob1, a_rob2,
        a_biN, a_bjN, oWB, Ea, Qa, last2, nh, N);
    } else {
      k_phase2m<0,1><<<dim3(G16), dim3(512), 0, stream>>>(m, x, xjb, WBb,
        a_rib1, a_rib2, a_db, a_u, a_rab1, a_rab2, a_rob1, a_rob2,
        a_biN, a_bjN, oWB, Ea, Qa, last2, nh, N);
    }
  }
  k_final<<<dim3((N+255)/256), dim3(256), 0, stream>>>(Z, Ea, Qa, Es, Eh, Qs, Qh, nh, outF, N, P);
}

// Round 13
// 519.215 us; speedup vs baseline: 1.1209x; 1.0570x over previous
//
#include <hip/hip_runtime.h>

typedef __attribute__((ext_vector_type(8))) short bfrag;   // 8 bf16 (4 VGPRs)
typedef __attribute__((ext_vector_type(4))) float ffrag;   // 4 fp32

__device__ __forceinline__ unsigned short f2b(float f){
  unsigned int u = __float_as_uint(f);
  return (unsigned short)((u + 0x7FFFu + ((u >> 16) & 1u)) >> 16);
}
// shifted softplus via v_exp/v_log (both base-2 on gfx950)
__device__ __forceinline__ float actf(float v){
  float e = __builtin_amdgcn_exp2f(-fabsf(v)*1.44269504088896341f);
  return fmaxf(v, 0.f) + __builtin_amdgcn_logf(1.f + e)*0.69314718055994531f - 0.69314718055994531f;
}

// ---------- small utility kernels ----------
__global__ __launch_bounds__(256) void k_zero(float* p, int n){
  int i = blockIdx.x*256 + threadIdx.x;
  if (i < n) p[i] = 0.f;
}

__global__ __launch_bounds__(256) void k_dij_count(
    const float* __restrict__ R, const int* __restrict__ idx_i, const int* __restrict__ idx_j,
    float* __restrict__ DijF, float* __restrict__ Dout, int* __restrict__ counts, int P){
  int p = blockIdx.x*256 + threadIdx.x;
  if (p >= P) return;
  int i = idx_i[p], j = idx_j[p];
  float dx = R[i*3+0] - R[j*3+0];
  float dy = R[i*3+1] - R[j*3+1];
  float dz = R[i*3+2] - R[j*3+2];
  float D = sqrtf(fmaxf(dx*dx + dy*dy + dz*dz, 0.f));
  DijF[p] = D;
  Dout[p] = D;
  atomicAdd(&counts[i], 1);
}

// hierarchical scan
__global__ __launch_bounds__(256) void k_scanA(const int* __restrict__ counts,
    int* __restrict__ locEx, int* __restrict__ bsum, int N){
  __shared__ int buf[256];
  int tid = threadIdx.x, idx = blockIdx.x*256 + tid;
  int v = (idx < N) ? counts[idx] : 0;
  buf[tid] = v;
  __syncthreads();
  for (int off = 1; off < 256; off <<= 1){
    int t = (tid >= off) ? buf[tid-off] : 0;
    __syncthreads();
    buf[tid] += t;
    __syncthreads();
  }
  if (idx < N) locEx[idx] = buf[tid] - v;
  if (tid == 255) bsum[blockIdx.x] = buf[255];
}
__global__ __launch_bounds__(64) void k_scanB(int* __restrict__ bsum,
    int* __restrict__ boff, int nb){
  if (threadIdx.x == 0){
    int acc = 0;
    for (int i = 0; i < nb; ++i){ boff[i] = acc; acc += bsum[i]; }
    boff[nb] = acc;
  }
}
__global__ __launch_bounds__(256) void k_scanC(const int* __restrict__ locEx,
    const int* __restrict__ boff, int* __restrict__ starts, int* __restrict__ cursor,
    int N, int nb){
  int idx = blockIdx.x*256 + threadIdx.x;
  if (idx < N){
    int s = locEx[idx] + boff[blockIdx.x];
    starts[idx] = s; cursor[idx] = s;
  }
  if (idx == 0) starts[N] = boff[nb];
}

__global__ __launch_bounds__(256) void k_scatter(const int* __restrict__ idx_i,
    const int* __restrict__ idx_j, const float* __restrict__ DijF,
    int* __restrict__ cursor, int* __restrict__ i_s, int* __restrict__ j_s,
    float* __restrict__ D_s, int P){
  int p = blockIdx.x*256 + threadIdx.x;
  if (p >= P) return;
  int i = idx_i[p];
  int pos = atomicAdd(&cursor[i], 1);
  i_s[pos] = i;
  j_s[pos] = idx_j[p];
  D_s[pos] = DijF[p];
}

__global__ __launch_bounds__(256) void k_rbf(
    const float* __restrict__ D_s, const float* __restrict__ cent, const float* __restrict__ wid,
    unsigned short* __restrict__ rbf_s, int P){
  int gid = blockIdx.x*256 + threadIdx.x;
  if (gid >= P*64) return;
  int t = gid >> 6, k = gid & 63;
  float D = D_s[t];
  float xc = D * 0.1f;
  float cut = 0.f;
  if (xc < 1.f){
    float x3 = xc*xc*xc, x4 = x3*xc, x5 = x4*xc;
    cut = 1.f - 6.f*x5 + 15.f*x4 - 10.f*x3;
  }
  float tt = expf(-D) - cent[k];
  rbf_s[gid] = f2b(cut * expf(-wid[k]*tt*tt));
}

// k2f B-frag prep -- unchanged, HW-verified
__global__ __launch_bounds__(256) void k_prep(const float* __restrict__ k2f,
    unsigned short* __restrict__ k2fP){
  int gid = blockIdx.x*256 + threadIdx.x;
  if (gid >= 5120) return;
  int l = gid & 63, fr = (gid >> 6) & 15, b = gid >> 10;
  int tile = fr >> 1, kh = fr & 1;
  const float* src = k2f + (size_t)b*64*128;
  int n = tile*16 + (l & 15);
  int kbase = kh*32 + (l >> 4)*8;
  ushort4 o0, o1;
  o0.x = f2b(src[(kbase+0)*128+n]); o0.y = f2b(src[(kbase+1)*128+n]);
  o0.z = f2b(src[(kbase+2)*128+n]); o0.w = f2b(src[(kbase+3)*128+n]);
  o1.x = f2b(src[(kbase+4)*128+n]); o1.y = f2b(src[(kbase+5)*128+n]);
  o1.z = f2b(src[(kbase+6)*128+n]); o1.w = f2b(src[(kbase+7)*128+n]);
  ushort4* dst = (ushort4*)(k2fP + (size_t)gid*8);
  dst[0] = o0; dst[1] = o1;
}

// ALL 75 weight matrices repacked in ONE launch (mapping as round 9)
__global__ __launch_bounds__(256) void k_prepAll(
    const float* __restrict__ riW1, const float* __restrict__ riW2,
    const float* __restrict__ dW,   const float* __restrict__ raW1,
    const float* __restrict__ raW2, const float* __restrict__ roW1,
    const float* __restrict__ roW2, const float* __restrict__ Wi,
    const float* __restrict__ Wj,   unsigned short* __restrict__ WBall){
  int gid = blockIdx.x*256 + threadIdx.x;
  if (gid >= 75*2048) return;
  int i = gid >> 11, r = gid & 2047;
  const float* S;
  int slot;
  if (i < 15)      { S = riW1 + (size_t)i*16384;      slot = (i/3)*15 + 2*(i%3); }
  else if (i < 30) { int j=i-15; S = riW2 + (size_t)j*16384; slot = (j/3)*15 + 2*(j%3) + 1; }
  else if (i < 35) { int j=i-30; S = dW   + (size_t)j*16384; slot = j*15 + 6; }
  else if (i < 45) { int j=i-35; S = raW1 + (size_t)j*16384; slot = (j/2)*15 + 7 + 2*(j%2); }
  else if (i < 55) { int j=i-45; S = raW2 + (size_t)j*16384; slot = (j/2)*15 + 8 + 2*(j%2); }
  else if (i < 60) { int j=i-55; S = roW1 + (size_t)j*16384; slot = j*15 + 11; }
  else if (i < 65) { int j=i-60; S = roW2 + (size_t)j*16384; slot = j*15 + 12; }
  else if (i < 70) { int j=i-65; S = Wi   + (size_t)j*16384; slot = ((j==0)?4:(j-1))*15 + 13; }
  else             { int j=i-70; S = Wj   + (size_t)j*16384; slot = ((j==0)?4:(j-1))*15 + 14; }
  int fr = r >> 6, l = r & 63;
  int T = fr >> 2, k0 = fr & 3;
  int n = T*16 + (l & 15);
  int kbase = k0*32 + (l >> 4)*8;
  unsigned short* D = WBall + ((size_t)slot*2048 + r)*8;
  ushort4 o0, o1;
  o0.x=f2b(S[(kbase+0)*128+n]); o0.y=f2b(S[(kbase+1)*128+n]);
  o0.z=f2b(S[(kbase+2)*128+n]); o0.w=f2b(S[(kbase+3)*128+n]);
  o1.x=f2b(S[(kbase+4)*128+n]); o1.y=f2b(S[(kbase+5)*128+n]);
  o1.z=f2b(S[(kbase+6)*128+n]); o1.w=f2b(S[(kbase+7)*128+n]);
  ((ushort4*)D)[0]=o0; ((ushort4*)D)[1]=o1;
}

// outW[b] [128x2] -> padded B-frags -- unchanged
__global__ __launch_bounds__(256) void k_prepO(const float* __restrict__ outW,
    unsigned short* __restrict__ outWB){
  int gid = blockIdx.x*256 + threadIdx.x;
  if (gid >= 5*256) return;
  int b = gid >> 8, r = gid & 255;
  int l = r & 63;
  int col = l & 15;
  int k0 = r >> 6;
  int kbase = k0*32 + (l >> 4)*8;
  ushort4 o0 = {0,0,0,0}, o1 = {0,0,0,0};
  if (col < 2){
    const float* S = outW + (size_t)b*256;
    o0.x=f2b(S[(kbase+0)*2+col]); o0.y=f2b(S[(kbase+1)*2+col]);
    o0.z=f2b(S[(kbase+2)*2+col]); o0.w=f2b(S[(kbase+3)*2+col]);
    o1.x=f2b(S[(kbase+4)*2+col]); o1.y=f2b(S[(kbase+5)*2+col]);
    o1.z=f2b(S[(kbase+6)*2+col]); o1.w=f2b(S[(kbase+7)*2+col]);
  }
  unsigned short* D = outWB + ((size_t)b*256 + r)*8;
  ((ushort4*)D)[0]=o0; ((ushort4*)D)[1]=o1;
}

// ---------- MFMA tile machinery ----------
// phase1 (2 waves, 4 col-tiles each)
__device__ __forceinline__ void mmtile(const unsigned short* tile,
    const unsigned short* __restrict__ WB, int w, int l, ffrag C[4]){
  int m = l & 15, q = l >> 4;
  bfrag A[4];
  #pragma unroll
  for (int k0 = 0; k0 < 4; ++k0)
    A[k0] = *(const bfrag*)(tile + m*136 + k0*32 + q*8);
  #pragma unroll
  for (int tt = 0; tt < 4; ++tt){
    ffrag c = {0.f,0.f,0.f,0.f};
    const bfrag* bp = (const bfrag*)(WB + (((w*4+tt)*4)*64 + l)*8);
    #pragma unroll
    for (int k0 = 0; k0 < 4; ++k0)
      c = __builtin_amdgcn_mfma_f32_16x16x32_bf16(A[k0], bp[k0*64], c, 0, 0, 0);
    C[tt] = c;
  }
}

// phase2 helpers: B in registers (8 bfrags per stage), wave w covers col-tiles w*2,w*2+1
__device__ __forceinline__ void loadB8(const unsigned short* __restrict__ WB,
    int w, int l, bfrag* B){
  #pragma unroll
  for (int tt = 0; tt < 2; ++tt)
    #pragma unroll
    for (int k0 = 0; k0 < 4; ++k0)
      B[tt*4+k0] = *(const bfrag*)(WB + ((size_t)((((w*2+tt)*4)+k0)*64 + l))*8);
}
__device__ __forceinline__ void mmB(const unsigned short* tile, const bfrag* B,
    int l, ffrag C[2]){
  int m = l & 15, q = l >> 4;
  bfrag A[4];
  #pragma unroll
  for (int k0 = 0; k0 < 4; ++k0)
    A[k0] = *(const bfrag*)(tile + m*136 + k0*32 + q*8);
  #pragma unroll
  for (int tt = 0; tt < 2; ++tt){
    ffrag c = {0.f,0.f,0.f,0.f};
    #pragma unroll
    for (int k0 = 0; k0 < 4; ++k0)
      c = __builtin_amdgcn_mfma_f32_16x16x32_bf16(A[k0], B[tt*4+k0], c, 0, 0, 0);
    C[tt] = c;
  }
}

// phase1: x = emb[Z]; m_g = act(act(x)@Wi0+bi0); xjb = act(act(x)@Wj0+bj0)
__global__ __launch_bounds__(128) void k_phase1m(
    const int* __restrict__ Z, const float* __restrict__ emb,
    const unsigned short* __restrict__ WB45,
    const float* __restrict__ bi0, const float* __restrict__ bj0,
    float* __restrict__ x_g, float* __restrict__ m_g, float* __restrict__ xjb_g, int N){
  __shared__ unsigned short tile[16*136];
  int tid = threadIdx.x, w = tid >> 6, l = tid & 63;
  int m = l & 15, q = l >> 4, rbase = blockIdx.x*16;
  #pragma unroll
  for (int r = 0; r < 4; ++r){
    int row = rbase + q*4 + r;
    int z = Z[row];
    #pragma unroll
    for (int tt = 0; tt < 4; ++tt){
      int c = (w*4+tt)*16 + m;
      float v = emb[(size_t)z*128 + c];
      x_g[(size_t)row*128 + c] = v;
      tile[(q*4+r)*136 + c] = f2b(actf(v));
    }
  }
  __syncthreads();
  ffrag C[4];
  mmtile(tile, WB45 + 13*16384, w, l, C);
  #pragma unroll
  for (int tt = 0; tt < 4; ++tt){
    int c = (w*4+tt)*16 + m;
    float bb = bi0[c];
    #pragma unroll
    for (int r = 0; r < 4; ++r)
      m_g[(size_t)(rbase + q*4 + r)*128 + c] = actf(C[tt][r] + bb);
  }
  mmtile(tile, WB45 + 14*16384, w, l, C);
  #pragma unroll
  for (int tt = 0; tt < 4; ++tt){
    int c = (w*4+tt)*16 + m;
    float bb = bj0[c];
    #pragma unroll
    for (int r = 0; r < 4; ++r)
      xjb_g[(size_t)(rbase + q*4 + r)*128 + c] = actf(C[tt][r] + bb);
  }
}

// MFMA pair-message, pipelined: prefetch next batch's A-frags + indices during
// the current batch's consume loop. (P % 512 == 0)
__global__ __launch_bounds__(256) void k_pairmsg2(
    const unsigned short* __restrict__ rbf_s, const unsigned short* __restrict__ k2fP,
    const int* __restrict__ i_s, const int* __restrict__ j_s,
    const float* __restrict__ xj, float* __restrict__ m_g, int P){
  __shared__ float G[4][16*130];
  int tid = threadIdx.x, w = tid >> 6, l = tid & 63;
  float* Gw = &G[w][0];
  bfrag B[16];
  #pragma unroll
  for (int t = 0; t < 8; ++t){
    #pragma unroll
    for (int kh = 0; kh < 2; ++kh)
      B[t*2+kh] = *(const bfrag*)(k2fP + (size_t)((t*2+kh)*64 + l)*8);
  }
  int wstart = (blockIdx.x*4 + w)*128;
  if (wstart >= P) return;
  int row16 = l & 15, quad = l >> 4;
  float a0 = 0.f, a1 = 0.f;
  int iCur = -1;
  bfrag A0 = *(const bfrag*)(rbf_s + (size_t)(wstart + row16)*64 + quad*8);
  bfrag A1 = *(const bfrag*)(rbf_s + (size_t)(wstart + row16)*64 + 32 + quad*8);
  int4 iv[4], jv[4];
  #pragma unroll
  for (int g = 0; g < 4; ++g){
    iv[g] = *(const int4*)(i_s + wstart + g*4);
    jv[g] = *(const int4*)(j_s + wstart + g*4);
  }
  #pragma unroll 1
  for (int bi2 = 0; bi2 < 8; ++bi2){
    int bt = wstart + bi2*16;
    const int* ip = (const int*)iv;
    const int* jp = (const int*)jv;
    float2 xv[16];
    #pragma unroll
    for (int k = 0; k < 16; ++k)
      xv[k] = *(const float2*)(xj + (size_t)jp[k]*128 + 2*l);
    #pragma unroll
    for (int t = 0; t < 8; ++t){
      ffrag C = {0.f,0.f,0.f,0.f};
      C = __builtin_amdgcn_mfma_f32_16x16x32_bf16(A0, B[t*2],   C, 0, 0, 0);
      C = __builtin_amdgcn_mfma_f32_16x16x32_bf16(A1, B[t*2+1], C, 0, 0, 0);
      #pragma unroll
      for (int r = 0; r < 4; ++r)
        Gw[(quad*4+r)*130 + t*16 + row16] = C[r];
    }
    bfrag nA0, nA1;
    int4 niv[4], njv[4];
    if (bi2 < 7){
      int btn = bt + 16;
      nA0 = *(const bfrag*)(rbf_s + (size_t)(btn + row16)*64 + quad*8);
      nA1 = *(const bfrag*)(rbf_s + (size_t)(btn + row16)*64 + 32 + quad*8);
      #pragma unroll
      for (int g = 0; g < 4; ++g){
        niv[g] = *(const int4*)(i_s + btn + g*4);
        njv[g] = *(const int4*)(j_s + btn + g*4);
      }
    }
    #pragma unroll
    for (int k = 0; k < 16; ++k){
      int i = ip[k];
      if (i != iCur){
        if (iCur >= 0){
          unsafeAtomicAdd(&m_g[(size_t)iCur*128 + 2*l],     a0);
          unsafeAtomicAdd(&m_g[(size_t)iCur*128 + 2*l + 1], a1);
        }
        iCur = i; a0 = 0.f; a1 = 0.f;
      }
      float g0 = Gw[k*130 + 2*l], g1 = Gw[k*130 + 2*l + 1];
      a0 = fmaf(g0, xv[k].x, a0);
      a1 = fmaf(g1, xv[k].y, a1);
    }
    if (bi2 < 7){
      A0 = nA0; A1 = nA1;
      #pragma unroll
      for (int g = 0; g < 4; ++g){ iv[g] = niv[g]; jv[g] = njv[g]; }
    }
  }
  if (iCur >= 0){
    unsafeAtomicAdd(&m_g[(size_t)iCur*128 + 2*l],     a0);
    unsafeAtomicAdd(&m_g[(size_t)iCur*128 + 2*l + 1], a1);
  }
}

// ---------- phase 2: pipelined stage loop, 4 waves / 16-row tile ----------
// W slots: riW1[l]=2l riW2[l]=2l+1 dW=6 raW1=7+2l raW2=8+2l roW1=11 roW2=12 WiN=13 WjN=14
// Stage seq (HASNEXT): 0,1,2,3,4,5,6,7,8,9,10,13,14,11,12 ; (!HASNEXT): 0..10,11,12
// Bias LDS: 0-2 rib1, 3-5 rib2, 6 db, 7 u, 8-9 rab1, 10-11 rab2, 12 rob1, 13 rob2, 14 biN, 15 bjN
template<int HASNEXT, int NH>
__global__ __launch_bounds__(256) void k_phase2m(
    float* __restrict__ m_g, float* __restrict__ x_g, float* __restrict__ xjb_g,
    const unsigned short* __restrict__ WBb,
    const float* __restrict__ rib1, const float* __restrict__ rib2,
    const float* __restrict__ db, const float* __restrict__ u,
    const float* __restrict__ rab1, const float* __restrict__ rab2,
    const float* __restrict__ rob1, const float* __restrict__ rob2,
    const float* __restrict__ biN, const float* __restrict__ bjN,
    const unsigned short* __restrict__ outWBb,
    float* __restrict__ Ea, float* __restrict__ Qa,
    float* __restrict__ last2, float* __restrict__ nh, int N){
  __shared__ unsigned short tiles[2][16*136];
  __shared__ float biasS[16*128];
  int tid = threadIdx.x, w = tid >> 6, l = tid & 63;
  int m = l & 15, q = l >> 4, rbase = blockIdx.x*16;
  ffrag mC[2], xC[2], C[2];
  int cur = 0;
  const int nst = HASNEXT ? 15 : 13;
  const int slotSeq[15] = {0,1,2,3,4,5,6,7,8,9,10,
                           HASNEXT?13:11, HASNEXT?14:12, 11, 12};
  bfrag Bb[2][8];
  loadB8(WBb + (size_t)slotSeq[0]*16384, w, l, Bb[0]);

  if (tid < 128){
    biasS[0*128+tid]  = rib1[tid];
    biasS[1*128+tid]  = rib1[128+tid];
    biasS[2*128+tid]  = rib1[256+tid];
    biasS[3*128+tid]  = rib2[tid];
    biasS[4*128+tid]  = rib2[128+tid];
    biasS[5*128+tid]  = rib2[256+tid];
    biasS[6*128+tid]  = db[tid];
    biasS[7*128+tid]  = u[tid];
    biasS[8*128+tid]  = rab1[tid];
    biasS[9*128+tid]  = rab1[128+tid];
    biasS[10*128+tid] = rab2[tid];
    biasS[11*128+tid] = rab2[128+tid];
    biasS[12*128+tid] = rob1[tid];
    biasS[13*128+tid] = rob2[tid];
    biasS[14*128+tid] = biN[tid];
    biasS[15*128+tid] = bjN[tid];
  }
  // preload x rows (used at stage 6)
  float xrow[2][4];
  #pragma unroll
  for (int tt = 0; tt < 2; ++tt){
    int c = (w*2+tt)*16 + m;
    #pragma unroll
    for (int r = 0; r < 4; ++r)
      xrow[tt][r] = x_g[(size_t)(rbase + q*4 + r)*128 + c];
  }
  // S0: load m -> mC; tiles[0] = act(m)
  #pragma unroll
  for (int tt = 0; tt < 2; ++tt){
    int c = (w*2+tt)*16 + m;
    #pragma unroll
    for (int r = 0; r < 4; ++r){
      float v = m_g[(size_t)(rbase + q*4 + r)*128 + c];
      mC[tt][r] = v;
      tiles[0][(q*4+r)*136 + c] = f2b(actf(v));
    }
  }
  #pragma unroll
  for (int s = 0; s < nst; ++s){
    __syncthreads();
    if (s+1 < nst) loadB8(WBb + (size_t)slotSeq[s+1]*16384, w, l, Bb[(s+1)&1]);
    mmB(tiles[cur], Bb[s&1], l, C);
    if (HASNEXT && s == 11){            // WiN -> m_g for next block
      #pragma unroll
      for (int tt = 0; tt < 2; ++tt){
        int c = (w*2+tt)*16 + m;
        float bb = biasS[14*128 + c];
        #pragma unroll
        for (int r = 0; r < 4; ++r)
          m_g[(size_t)(rbase + q*4 + r)*128 + c] = actf(C[tt][r] + bb);
      }
    } else if (HASNEXT && s == 12){     // WjN -> xjb for next block
      #pragma unroll
      for (int tt = 0; tt < 2; ++tt){
        int c = (w*2+tt)*16 + m;
        float bb = biasS[15*128 + c];
        #pragma unroll
        for (int r = 0; r < 4; ++r)
          xjb_g[(size_t)(rbase + q*4 + r)*128 + c] = actf(C[tt][r] + bb);
      }
    } else if (s == 6){                 // x-update
      #pragma unroll
      for (int tt = 0; tt < 2; ++tt){
        int c = (w*2+tt)*16 + m;
        float uu = biasS[7*128 + c], bb = biasS[6*128 + c];
        #pragma unroll
        for (int r = 0; r < 4; ++r){
          float nv = uu*xrow[tt][r] + C[tt][r] + bb;
          xC[tt][r] = nv;
          tiles[1-cur][(q*4+r)*136 + c] = f2b(actf(nv));
        }
      }
      cur ^= 1;
    } else if (s == 1 || s == 3 || s == 5){   // m-residual close
      #pragma unroll
      for (int tt = 0; tt < 2; ++tt){
        int c = (w*2+tt)*16 + m;
        float bb = biasS[(3 + (s>>1))*128 + c];
        #pragma unroll
        for (int r = 0; r < 4; ++r){
          float nv = mC[tt][r] + C[tt][r] + bb;
          mC[tt][r] = nv;
          tiles[1-cur][(q*4+r)*136 + c] = f2b(actf(nv));
        }
      }
      cur ^= 1;
    } else if (s == 8 || s == 10){            // x-residual close
      #pragma unroll
      for (int tt = 0; tt < 2; ++tt){
        int c = (w*2+tt)*16 + m;
        float bb = biasS[(10 + ((s-8)>>1))*128 + c];
        #pragma unroll
        for (int r = 0; r < 4; ++r){
          float nv = xC[tt][r] + C[tt][r] + bb;
          xC[tt][r] = nv;
          tiles[1-cur][(q*4+r)*136 + c] = f2b(actf(nv));
          if (HASNEXT && s == 10)
            x_g[(size_t)(rbase + q*4 + r)*128 + c] = nv;
        }
      }
      cur ^= 1;
    } else if ((HASNEXT && s == 14) || (!HASNEXT && s == 12)){  // o = x + h@roW2 + b
      #pragma unroll
      for (int tt = 0; tt < 2; ++tt){
        int c = (w*2+tt)*16 + m;
        float bb = biasS[13*128 + c];
        #pragma unroll
        for (int r = 0; r < 4; ++r){
          float ov = xC[tt][r] + C[tt][r] + bb;
          tiles[1-cur][(q*4+r)*136 + c] = f2b(actf(ov));
        }
      }
      cur ^= 1;
    } else {                                  // act-only stages
      int bidx = (s==0)?0:(s==2)?1:(s==4)?2:(s==7)?8:(s==9)?9:12;
      #pragma unroll
      for (int tt = 0; tt < 2; ++tt){
        int c = (w*2+tt)*16 + m;
        float bb = biasS[bidx*128 + c];
        #pragma unroll
        for (int r = 0; r < 4; ++r)
          tiles[1-cur][(q*4+r)*136 + c] = f2b(actf(C[tt][r] + bb));
      }
      cur ^= 1;
    }
  }
  // head: out = act(o) @ outW (padded to 16 cols), wave 0 only
  __syncthreads();
  if (w == 0){
    bfrag A[4];
    #pragma unroll
    for (int k0 = 0; k0 < 4; ++k0)
      A[k0] = *(const bfrag*)(&tiles[cur][0] + m*136 + k0*32 + q*8);
    ffrag Ch = {0.f,0.f,0.f,0.f};
    #pragma unroll
    for (int k0 = 0; k0 < 4; ++k0){
      bfrag B = *(const bfrag*)(outWBb + (size_t)(k0*64 + l)*8);
      Ch = __builtin_amdgcn_mfma_f32_16x16x32_bf16(A[k0], B, Ch, 0, 0, 0);
    }
    int col = m;
    if (col < 2){
      float tp = 0.f;
      #pragma unroll
      for (int r = 0; r < 4; ++r){
        int row = rbase + q*4 + r;
        float val = Ch[r];
        if (col == 0) Ea[row] += val; else Qa[row] += val;
        float sq = val*val;
        if (NH){
          float lastv = last2[row*2 + col];
          tp += sq/(sq + lastv + 1e-7f);
        }
        last2[row*2 + col] = sq;
      }
      if (NH) unsafeAtomicAdd(nh, tp);
    }
  }
}

__global__ __launch_bounds__(256) void k_final(
    const int* __restrict__ Z, const float* __restrict__ Ea, const float* __restrict__ Qa,
    const float* __restrict__ Es, const float* __restrict__ Eh,
    const float* __restrict__ Qs, const float* __restrict__ Qh,
    const float* __restrict__ nh, float* __restrict__ out, int N, int P){
  int n = blockIdx.x*256 + threadIdx.x;
  if (n < N){
    int z = Z[n];
    out[n]   = Es[z]*Ea[n] + Eh[z];
    out[N+n] = Qs[z]*Qa[n] + Qh[z];
  }
  if (blockIdx.x == 0 && threadIdx.x == 0)
    out[(size_t)2*N + P] = nh[0] / (2.f * (float)N);
}

extern "C" void kernel_launch(void* const* d_in, const int* in_sizes, int n_in,
                              void* d_out, int out_size, void* d_ws, size_t ws_size,
                              hipStream_t stream){
  const int N = in_sizes[0];
  const int P = in_sizes[2];
  const int F = 128;

  const int* Z      = (const int*)d_in[0];
  const float* R    = (const float*)d_in[1];
  const int* idx_i  = (const int*)d_in[2];
  const int* idx_j  = (const int*)d_in[3];
  const float* emb  = (const float*)d_in[4];
  const float* cent = (const float*)d_in[5];
  const float* wid  = (const float*)d_in[6];
  const float* k2f  = (const float*)d_in[7];
  const float* Wi   = (const float*)d_in[8];  const float* bi   = (const float*)d_in[9];
  const float* Wj   = (const float*)d_in[10]; const float* bj   = (const float*)d_in[11];
  const float* riW1 = (const float*)d_in[12]; const float* rib1 = (const float*)d_in[13];
  const float* riW2 = (const float*)d_in[14]; const float* rib2 = (const float*)d_in[15];
  const float* dWp  = (const float*)d_in[16]; const float* dbp  = (const float*)d_in[17];
  const float* u    = (const float*)d_in[18];
  const float* raW1 = (const float*)d_in[19]; const float* rab1 = (const float*)d_in[20];
  const float* raW2 = (const float*)d_in[21]; const float* rab2 = (const float*)d_in[22];
  const float* roW1 = (const float*)d_in[23]; const float* rob1 = (const float*)d_in[24];
  const float* roW2 = (const float*)d_in[25]; const float* rob2 = (const float*)d_in[26];
  const float* outW = (const float*)d_in[27];
  const float* Es   = (const float*)d_in[28]; const float* Eh   = (const float*)d_in[29];
  const float* Qs   = (const float*)d_in[30]; const float* Qh   = (const float*)d_in[31];

  char* ws = (char*)d_ws;
  size_t off = 0;
  float* DijF  = (float*)(ws + off); off += (size_t)P*4;
  float* D_s   = (float*)(ws + off); off += (size_t)P*4;
  int*   i_s   = (int*)  (ws + off); off += (size_t)P*4;
  int*   j_s   = (int*)  (ws + off); off += (size_t)P*4;
  unsigned short* rbf_s = (unsigned short*)(ws + off); off += (size_t)P*64*2;
  unsigned short* k2fP  = (unsigned short*)(ws + off); off += (size_t)5*16*64*8*2;
  unsigned short* WBall = (unsigned short*)(ws + off); off += (size_t)75*16384*2;
  unsigned short* outWB = (unsigned short*)(ws + off); off += (size_t)5*2048*2;
  float* x     = (float*)(ws + off); off += (size_t)N*F*4;
  float* xjb   = (float*)(ws + off); off += (size_t)N*F*4;
  float* m     = (float*)(ws + off); off += (size_t)N*F*4;
  float* last2 = (float*)(ws + off); off += (size_t)N*2*4;
  float* Ea    = (float*)(ws + off); off += (size_t)N*4;   // zero region start
  float* Qa    = (float*)(ws + off); off += (size_t)N*4;
  float* nh    = (float*)(ws + off); off += 256;
  int*   counts= (int*)  (ws + off); off += (size_t)N*4;   // zero region end
  int*   starts= (int*)  (ws + off); off += (size_t)(N+1)*4;
  int*   cursor= (int*)  (ws + off); off += (size_t)N*4;
  int*   locEx = (int*)  (ws + off); off += (size_t)N*4;
  int*   bsum  = (int*)  (ws + off); off += 64*4;
  int*   boff  = (int*)  (ws + off); off += 68*4;

  float* outF = (float*)d_out;
  float* Dout = outF + (size_t)2*N;

  const int nb = (N + 255)/256;   // 40
  const int nzero = 3*N + 64;
  k_zero<<<dim3((nzero+255)/256), dim3(256), 0, stream>>>(Ea, nzero);
  k_dij_count<<<dim3((P+255)/256), dim3(256), 0, stream>>>(R, idx_i, idx_j, DijF, Dout, counts, P);
  k_scanA<<<dim3(nb), dim3(256), 0, stream>>>(counts, locEx, bsum, N);
  k_scanB<<<dim3(1), dim3(64), 0, stream>>>(bsum, boff, nb);
  k_scanC<<<dim3(nb), dim3(256), 0, stream>>>(locEx, boff, starts, cursor, N, nb);
  k_scatter<<<dim3((P+255)/256), dim3(256), 0, stream>>>(idx_i, idx_j, DijF, cursor, i_s, j_s, D_s, P);
  k_rbf<<<dim3((P*64+255)/256), dim3(256), 0, stream>>>(D_s, cent, wid, rbf_s, P);
  k_prep<<<dim3(20), dim3(256), 0, stream>>>(k2f, k2fP);
  k_prepAll<<<dim3((75*2048+255)/256), dim3(256), 0, stream>>>(riW1, riW2, dWp, raW1, raW2,
                                                               roW1, roW2, Wi, Wj, WBall);
  k_prepO<<<dim3(5), dim3(256), 0, stream>>>(outW, outWB);

  const int G16 = (N + 15)/16;   // 625
  k_phase1m<<<dim3(G16), dim3(128), 0, stream>>>(Z, emb, WBall + (size_t)4*15*16384,
                                                 bi, bj, x, m, xjb, N);

  const int pmg = (P + 511)/512;
  for (int b = 0; b < 5; ++b){
    k_pairmsg2<<<dim3(pmg), dim3(256), 0, stream>>>(rbf_s, k2fP + (size_t)b*16*64*8,
                                                    i_s, j_s, xjb, m, P);
    const unsigned short* WBb = WBall + (size_t)b*15*16384;
    const float* a_rib1 = rib1 + (size_t)b*3*F;
    const float* a_rib2 = rib2 + (size_t)b*3*F;
    const float* a_db   = dbp  + (size_t)b*F;
    const float* a_u    = u    + (size_t)b*F;
    const float* a_rab1 = rab1 + (size_t)b*2*F;
    const float* a_rab2 = rab2 + (size_t)b*2*F;
    const float* a_rob1 = rob1 + (size_t)b*F;
    const float* a_rob2 = rob2 + (size_t)b*F;
    int bn = (b < 4) ? (b+1) : 0;
    const float* a_biN = bi + (size_t)bn*F;
    const float* a_bjN = bj + (size_t)bn*F;
    const unsigned short* oWB = outWB + (size_t)b*2048;
    if (b == 0){
      k_phase2m<1,0><<<dim3(G16), dim3(256), 0, stream>>>(m, x, xjb, WBb,
        a_rib1, a_rib2, a_db, a_u, a_rab1, a_rab2, a_rob1, a_rob2,
        a_biN, a_bjN, oWB, Ea, Qa, last2, nh, N);
    } else if (b < 4){
      k_phase2m<1,1><<<dim3(G16), dim3(256), 0, stream>>>(m, x, xjb, WBb,
        a_rib1, a_rib2, a_db, a_u, a_rab1, a_rab2, a_rob1, a_rob2,
        a_biN, a_bjN, oWB, Ea, Qa, last2, nh, N);
    } else {
      k_phase2m<0,1><<<dim3(G16), dim3(256), 0, stream>>>(m, x, xjb, WBb,
        a_rib1, a_rib2, a_db, a_u, a_rab1, a_rab2, a_rob1, a_rob2,
        a_biN, a_bjN, oWB, Ea, Qa, last2, nh, N);
    }
  }
  k_final<<<dim3((N+255)/256), dim3(256), 0, stream>>>(Z, Ea, Qa, Es, Eh, Qs, Qh, nh, outF, N, P);
}